// Round 3
// baseline (668.573 us; speedup 1.0000x reference)
//
#include <hip/hip_runtime.h>

// ---------- common ----------
typedef short sh8 __attribute__((ext_vector_type(8)));
typedef float f32x4 __attribute__((ext_vector_type(4)));

#define DEV __device__ __forceinline__

DEV f32x4 mfma16(sh8 a, sh8 b, f32x4 c) {
  return __builtin_amdgcn_mfma_f32_16x16x32_bf16(a, b, c, 0, 0, 0);
}

DEV unsigned short f2bf(float f) {
  unsigned u = __float_as_uint(f);
  u = u + 0x7FFFu + ((u >> 16) & 1u);   // RNE
  return (unsigned short)(u >> 16);
}

DEV unsigned cvtpk(float lo, float hi) {
  unsigned r;
  asm("v_cvt_pk_bf16_f32 %0, %1, %2" : "=v"(r) : "v"(lo), "v"(hi));
  return r;
}

DEV void gll16(const void* g, void* l) {
  __builtin_amdgcn_global_load_lds(
      (const __attribute__((address_space(1))) unsigned int*)g,
      (__attribute__((address_space(3))) unsigned int*)l, 16, 0, 0);
}

// ---------- kernel 1: x fp32 -> bf16 ----------
__global__ void cvt_x_kernel(const float* __restrict__ x, unsigned short* __restrict__ xb, int n4) {
  int i = blockIdx.x * blockDim.x + threadIdx.x;
  int stride = gridDim.x * blockDim.x;
  for (; i < n4; i += stride) {
    float4 v = ((const float4*)x)[i];
    ushort4 o;
    o.x = f2bf(v.x); o.y = f2bf(v.y); o.z = f2bf(v.z); o.w = f2bf(v.w);
    ((ushort4*)xb)[i] = o;
  }
}

// ---------- kernel 2: weight transpose + cvt (512x512 fp32 [K][N] -> bf16 [N][K]) ----------
__global__ void cvt_wT_kernel(const float* __restrict__ W0, const float* __restrict__ W1,
                              const float* __restrict__ W2, const float* __restrict__ W3,
                              unsigned short* __restrict__ T0, unsigned short* __restrict__ T1,
                              unsigned short* __restrict__ T2, unsigned short* __restrict__ T3) {
  const float* W; unsigned short* T;
  switch (blockIdx.z) {
    case 0: W = W0; T = T0; break;
    case 1: W = W1; T = T1; break;
    case 2: W = W2; T = T2; break;
    default: W = W3; T = T3; break;
  }
  __shared__ float tile[32][33];
  int tx = threadIdx.x & 31, ty = threadIdx.x >> 5;
  int r0 = blockIdx.y * 32, c0 = blockIdx.x * 32;
#pragma unroll
  for (int i = 0; i < 4; i++) tile[ty + i * 8][tx] = W[(r0 + ty + i * 8) * 512 + c0 + tx];
  __syncthreads();
#pragma unroll
  for (int i = 0; i < 4; i++) T[(c0 + ty + i * 8) * 512 + r0 + tx] = f2bf(tile[tx][ty + i * 8]);
}

// ---------- kernel 3: GEMM  C[M,512] = A[M,K]*Bt[512,K]^T + bias ----------
template <bool BF16OUT>
__global__ __launch_bounds__(256, 2) void gemm_bt_kernel(
    const unsigned short* __restrict__ A,
    const unsigned short* __restrict__ Bt0, const unsigned short* __restrict__ Bt1,
    const unsigned short* __restrict__ Bt2,
    const float* __restrict__ b0, const float* __restrict__ b1, const float* __restrict__ b2,
    void* __restrict__ C0, void* __restrict__ C1, void* __restrict__ C2,
    int M, int K) {
  const unsigned short* Bt; const float* bias; void* Cv;
  switch (blockIdx.z) {
    case 0: Bt = Bt0; bias = b0; Cv = C0; break;
    case 1: Bt = Bt1; bias = b1; Cv = C1; break;
    default: Bt = Bt2; bias = b2; Cv = C2; break;
  }
  __shared__ __align__(16) unsigned short As[128 * 32];
  __shared__ __align__(16) unsigned short Bs[128 * 32];
  int tid = threadIdx.x;
  int lane = tid & 63, w = tid >> 6;
  int g = lane >> 4, r = lane & 15;
  int wr = w >> 1, wc = w & 1;
  int brow = blockIdx.x * 128, bcol = blockIdx.y * 128;
  f32x4 acc[4][4] = {};
  int nk = K >> 5;
  for (int ks = 0; ks < nk; ks++) {
#pragma unroll
    for (int cc = 0; cc < 2; cc++) {
      int c = tid + cc * 256;
      int row = c >> 2, k8 = (c & 3) * 8;
      uint4 va = *(const uint4*)&A[(size_t)(brow + row) * K + ks * 32 + k8];
      uint4 vb = *(const uint4*)&Bt[(size_t)(bcol + row) * K + ks * 32 + k8];
      *(uint4*)&As[row * 32 + k8] = va;
      *(uint4*)&Bs[row * 32 + k8] = vb;
    }
    __syncthreads();
    sh8 af[4], bfr[4];
#pragma unroll
    for (int m = 0; m < 4; m++) af[m] = *(const sh8*)&As[(wr * 64 + m * 16 + r) * 32 + g * 8];
#pragma unroll
    for (int n = 0; n < 4; n++) bfr[n] = *(const sh8*)&Bs[(wc * 64 + n * 16 + r) * 32 + g * 8];
#pragma unroll
    for (int m = 0; m < 4; m++)
#pragma unroll
      for (int n = 0; n < 4; n++) acc[m][n] = mfma16(af[m], bfr[n], acc[m][n]);
    __syncthreads();
  }
#pragma unroll
  for (int n = 0; n < 4; n++) {
    int col = bcol + wc * 64 + n * 16 + r;
    float bv = bias[col];
#pragma unroll
    for (int m = 0; m < 4; m++) {
      int row = brow + wr * 64 + m * 16 + g * 4;
#pragma unroll
      for (int i = 0; i < 4; i++) {
        float v = acc[m][n][i] + bv;
        if (BF16OUT) ((unsigned short*)Cv)[(size_t)(row + i) * 512 + col] = f2bf(v);
        else         ((float*)Cv)[(size_t)(row + i) * 512 + col] = v;
      }
    }
  }
}

// ---------- kernel 4: v [8192][512] -> vT [512][8192] (bf16) ----------
__global__ void transpose_v_kernel(const unsigned short* __restrict__ in, unsigned short* __restrict__ out) {
  __shared__ unsigned short tile[32][33];
  int tx = threadIdx.x & 31, ty = threadIdx.x >> 5;
  int r0 = blockIdx.y * 32, c0 = blockIdx.x * 32;
#pragma unroll
  for (int i = 0; i < 4; i++) tile[ty + i * 8][tx] = in[(size_t)(r0 + ty + i * 8) * 512 + c0 + tx];
  __syncthreads();
#pragma unroll
  for (int i = 0; i < 4; i++) out[(size_t)(c0 + ty + i * 8) * 8192 + r0 + tx] = tile[tx][ty + i * 8];
}

// ---------- kernel 5: flash attention ----------
// grid 128*NS blocks; split = bx & (NS-1) (XCD-affine for NS=4), qblk = bx >> log2(NS).
// block = 4 waves x 16 q-rows. KVBLK=32. K double-buffered in LDS via
// global_load_lds (XOR-swizzled source, linear dest). V-frags read directly
// from global VT (L2-resident slice per XCD). Swapped QK^T: S^T = K*Q^T so
// q is the lane-local column; softmax needs only 4 bpermutes/step.
__global__ __launch_bounds__(256, 2) void flash_kernel(
    const unsigned short* __restrict__ Q,   // [8192][512] bf16
    const unsigned short* __restrict__ Kb,  // [8192][512] bf16
    const unsigned short* __restrict__ VT,  // [512][8192] bf16
    float* __restrict__ Pout,               // [NS][8192][512] fp32 partials
    float* __restrict__ ML,                 // [NS][2][8192]
    int nsLog2) {
  __shared__ __align__(16) unsigned short k_lds[2][32][512];  // XOR-swizzled cols
  __shared__ __align__(16) unsigned short p_lds[4][16][32];

  const int tid = threadIdx.x;
  const int lane = tid & 63, w = tid >> 6;
  const int g = lane >> 4, r = lane & 15;
  const int ns = 1 << nsLog2;
  const int split = blockIdx.x & (ns - 1);
  const int qblk = blockIdx.x >> nsLog2;
  const int qbase = qblk * 64 + w * 16;
  const int kvlen = 8192 >> nsLog2;
  const int kv0 = split * kvlen;
  const int nsteps = kvlen >> 5;

  // Q fragments (B-operand layout for swapped mfma): lane holds Q[qbase+r][.]
  sh8 qa[16];
#pragma unroll
  for (int dc = 0; dc < 16; dc++)
    qa[dc] = *(const sh8*)&Q[(qbase + r) * 512 + dc * 32 + g * 8];

  f32x4 acc[32] = {};
  float mrow = -1e30f, lrow = 0.f;
  const float K2r = 0.04419417382415922f * 1.4426950408889634f;  // 1/sqrt(512)*log2e
  const int swz = (r & 7) * 8;

  // prologue: stage K tile 0 (wave w stages rows w*8..w*8+7)
#pragma unroll
  for (int ii = 0; ii < 8; ii++) {
    int row = w * 8 + ii;
    gll16(Kb + (size_t)(kv0 + row) * 512 + (size_t)((lane ^ ii) * 8), &k_lds[0][row][0]);
  }

  int cur = 0;
  for (int s = 0; s < nsteps; s++) {
    const int kvrow0 = kv0 + s * 32;
    asm volatile("s_waitcnt vmcnt(0)" ::: "memory");
    __syncthreads();  // tile s visible to all waves; everyone done with tile s-1
    if (s + 1 < nsteps) {
#pragma unroll
      for (int ii = 0; ii < 8; ii++) {
        int row = w * 8 + ii;
        gll16(Kb + (size_t)(kvrow0 + 32 + row) * 512 + (size_t)((lane ^ ii) * 8),
              &k_lds[cur ^ 1][row][0]);
      }
    }

    // QK^T swapped: S^T[kv][q] ; A = K rows (LDS), B = Q (regs)
    f32x4 sA0 = {0.f, 0.f, 0.f, 0.f};
    f32x4 sA1 = {0.f, 0.f, 0.f, 0.f};
#pragma unroll
    for (int dc = 0; dc < 16; dc++) {
      int co = (dc * 32 + g * 8) ^ swz;
      sh8 kf0 = *(const sh8*)&k_lds[cur][r][co];
      sh8 kf1 = *(const sh8*)&k_lds[cur][16 + r][co];
      sA0 = mfma16(kf0, qa[dc], sA0);
      sA1 = mfma16(kf1, qa[dc], sA1);
    }

    // online softmax: this lane owns column q = qbase + r (8 scores)
    float rmax = fmaxf(fmaxf(fmaxf(sA0[0], sA0[1]), fmaxf(sA0[2], sA0[3])),
                       fmaxf(fmaxf(sA1[0], sA1[1]), fmaxf(sA1[2], sA1[3])));
    rmax = fmaxf(rmax, __shfl_xor(rmax, 16));
    rmax = fmaxf(rmax, __shfl_xor(rmax, 32));
    float tmax = rmax * K2r;
    if (__any(tmax > mrow + 4.0f)) {   // defer-max THR=4
      float mn = fmaxf(mrow, tmax);
      float corr = __builtin_amdgcn_exp2f(mrow - mn);
      mrow = mn;
      lrow *= corr;
      f32x4 cv;
      cv[0] = __shfl(corr, 4 * g + 0);
      cv[1] = __shfl(corr, 4 * g + 1);
      cv[2] = __shfl(corr, 4 * g + 2);
      cv[3] = __shfl(corr, 4 * g + 3);
#pragma unroll
      for (int dt = 0; dt < 32; dt++) acc[dt] *= cv;
    }
    float p0 = __builtin_amdgcn_exp2f(fmaf(sA0[0], K2r, -mrow));
    float p1 = __builtin_amdgcn_exp2f(fmaf(sA0[1], K2r, -mrow));
    float p2 = __builtin_amdgcn_exp2f(fmaf(sA0[2], K2r, -mrow));
    float p3 = __builtin_amdgcn_exp2f(fmaf(sA0[3], K2r, -mrow));
    float p4 = __builtin_amdgcn_exp2f(fmaf(sA1[0], K2r, -mrow));
    float p5 = __builtin_amdgcn_exp2f(fmaf(sA1[1], K2r, -mrow));
    float p6 = __builtin_amdgcn_exp2f(fmaf(sA1[2], K2r, -mrow));
    float p7 = __builtin_amdgcn_exp2f(fmaf(sA1[3], K2r, -mrow));
    float ps = ((p0 + p1) + (p2 + p3)) + ((p4 + p5) + (p6 + p7));
    ps += __shfl_xor(ps, 16);
    ps += __shfl_xor(ps, 32);
    lrow += ps;

    // P^T -> p_lds[q][k] (packed bf16 pairs), then PV A-frag read
    uint2 w0, w1;
    w0.x = cvtpk(p0, p1); w0.y = cvtpk(p2, p3);
    w1.x = cvtpk(p4, p5); w1.y = cvtpk(p6, p7);
    *(uint2*)&p_lds[w][r][4 * g] = w0;
    *(uint2*)&p_lds[w][r][16 + 4 * g] = w1;

    // PV: acc[16 q][512 d] += P[16][32] * V[32][512]; V-frags from global VT
    sh8 pf = *(const sh8*)&p_lds[w][r][8 * g];
#pragma unroll
    for (int dt = 0; dt < 32; dt++) {
      sh8 vf = *(const sh8*)&VT[(dt * 16 + r) * 8192 + kvrow0 + g * 8];
      acc[dt] = mfma16(pf, vf, acc[dt]);
    }
    cur ^= 1;
  }

  float* P = Pout + (size_t)split * 4194304;
#pragma unroll
  for (int dt = 0; dt < 32; dt++) {
#pragma unroll
    for (int i = 0; i < 4; i++) {
      P[(qbase + 4 * g + i) * 512 + dt * 16 + r] = acc[dt][i];
    }
  }
  if (g == 0) {
    ML[(split * 2 + 0) * 8192 + qbase + r] = mrow;
    ML[(split * 2 + 1) * 8192 + qbase + r] = lrow;
  }
}

// ---------- kernel 6: merge KV-split partials -> attended bf16 ----------
template <int NS>
__global__ void combine_kernel(const float* __restrict__ Pp, const float* __restrict__ ML,
                               unsigned short* __restrict__ att) {
  int idx = blockIdx.x * blockDim.x + threadIdx.x;
  int stride = gridDim.x * blockDim.x;
  for (int i4 = idx; i4 < 8192 * 512 / 4; i4 += stride) {
    int row = i4 >> 7;
    float m[NS], l[NS], e[NS];
    float mm = -1e30f;
#pragma unroll
    for (int s2 = 0; s2 < NS; s2++) {
      m[s2] = ML[(s2 * 2 + 0) * 8192 + row];
      l[s2] = ML[(s2 * 2 + 1) * 8192 + row];
      mm = fmaxf(mm, m[s2]);
    }
    float den = 0.f;
#pragma unroll
    for (int s2 = 0; s2 < NS; s2++) {
      e[s2] = __builtin_amdgcn_exp2f(m[s2] - mm);
      den += l[s2] * e[s2];
    }
    float inv = 1.0f / den;
    float ox = 0.f, oy = 0.f, oz = 0.f, ow = 0.f;
#pragma unroll
    for (int s2 = 0; s2 < NS; s2++) {
      float4 a = ((const float4*)(Pp + (size_t)s2 * 4194304))[i4];
      ox += a.x * e[s2]; oy += a.y * e[s2]; oz += a.z * e[s2]; ow += a.w * e[s2];
    }
    ushort4 ov;
    ov.x = f2bf(ox * inv); ov.y = f2bf(oy * inv);
    ov.z = f2bf(oz * inv); ov.w = f2bf(ow * inv);
    ((ushort4*)att)[i4] = ov;
  }
}

// ---------- launch ----------
extern "C" void kernel_launch(void* const* d_in, const int* in_sizes, int n_in,
                              void* d_out, int out_size, void* d_ws, size_t ws_size,
                              hipStream_t stream) {
  const float* x  = (const float*)d_in[0];
  const float* Wq = (const float*)d_in[1];
  const float* bq = (const float*)d_in[2];
  const float* Wk = (const float*)d_in[3];
  const float* bk = (const float*)d_in[4];
  const float* Wv = (const float*)d_in[5];
  const float* bv = (const float*)d_in[6];
  const float* Wo = (const float*)d_in[7];
  const float* bo = (const float*)d_in[8];

  char* ws = (char*)d_ws;
  unsigned short* xb  = (unsigned short*)(ws + 0);          //  8 MB
  unsigned short* qb  = (unsigned short*)(ws + 8388608);    //  8 MB
  unsigned short* kb  = (unsigned short*)(ws + 16777216);   //  8 MB
  unsigned short* vb  = (unsigned short*)(ws + 25165824);   //  8 MB
  unsigned short* vtb = (unsigned short*)(ws + 33554432);   //  8 MB
  unsigned short* att = (unsigned short*)(ws + 41943040);   //  8 MB
  unsigned short* wqT = (unsigned short*)(ws + 50331648);   // 0.5 MB each
  unsigned short* wkT = (unsigned short*)(ws + 50855936);
  unsigned short* wvT = (unsigned short*)(ws + 51380224);
  unsigned short* woT = (unsigned short*)(ws + 51904512);
  float* ml   = (float*)(ws + 52428800);                    // up to 256 KB
  float* part = (float*)(ws + 52690944);                    // NS x 16 MB fp32

  // KV-split count: 4 needs ~114.3 MB of workspace, else fall back to 2 (82.3 MB).
  int nsLog2 = (ws_size >= 119900000ull) ? 2 : 1;
  int NS = 1 << nsLog2;

  cvt_x_kernel<<<2048, 256, 0, stream>>>(x, xb, 8192 * 512 / 4);
  cvt_wT_kernel<<<dim3(16, 16, 4), 256, 0, stream>>>(Wq, Wk, Wv, Wo, wqT, wkT, wvT, woT);
  gemm_bt_kernel<true><<<dim3(64, 4, 3), 256, 0, stream>>>(
      xb, wqT, wkT, wvT, bq, bk, bv, qb, kb, vb, 8192, 512);
  transpose_v_kernel<<<dim3(16, 256), 256, 0, stream>>>(vb, vtb);
  flash_kernel<<<128 * NS, 256, 0, stream>>>(qb, kb, vtb, part, ml, nsLog2);
  if (NS == 4) combine_kernel<4><<<1024, 256, 0, stream>>>(part, ml, att);
  else         combine_kernel<2><<<1024, 256, 0, stream>>>(part, ml, att);
  gemm_bt_kernel<false><<<dim3(64, 4, 1), 256, 0, stream>>>(
      att, woT, nullptr, nullptr, bo, nullptr, nullptr, (float*)d_out, nullptr, nullptr, 8192, 512);
}

// Round 4
// 318.042 us; speedup vs baseline: 2.1022x; 2.1022x over previous
//
#include <hip/hip_runtime.h>

// ---------- common ----------
typedef short sh8 __attribute__((ext_vector_type(8)));
typedef float f32x4 __attribute__((ext_vector_type(4)));

#define DEV __device__ __forceinline__

DEV f32x4 mfma16(sh8 a, sh8 b, f32x4 c) {
  return __builtin_amdgcn_mfma_f32_16x16x32_bf16(a, b, c, 0, 0, 0);
}

DEV unsigned short f2bf(float f) {
  unsigned u = __float_as_uint(f);
  u = u + 0x7FFFu + ((u >> 16) & 1u);   // RNE
  return (unsigned short)(u >> 16);
}

DEV unsigned cvtpk(float lo, float hi) {
  unsigned r;
  asm("v_cvt_pk_bf16_f32 %0, %1, %2" : "=v"(r) : "v"(lo), "v"(hi));
  return r;
}

DEV void gll16(const void* g, void* l) {
  __builtin_amdgcn_global_load_lds(
      (const __attribute__((address_space(1))) unsigned int*)g,
      (__attribute__((address_space(3))) unsigned int*)l, 16, 0, 0);
}

DEV float bf2f(unsigned short u) { return __uint_as_float(((unsigned)u) << 16); }

// ---------- kernel 1: x fp32 -> bf16 ----------
__global__ void cvt_x_kernel(const float* __restrict__ x, unsigned short* __restrict__ xb, int n4) {
  int i = blockIdx.x * blockDim.x + threadIdx.x;
  int stride = gridDim.x * blockDim.x;
  for (; i < n4; i += stride) {
    float4 v = ((const float4*)x)[i];
    ushort4 o;
    o.x = f2bf(v.x); o.y = f2bf(v.y); o.z = f2bf(v.z); o.w = f2bf(v.w);
    ((ushort4*)xb)[i] = o;
  }
}

// ---------- kernel 2: weight transpose + cvt (512x512 fp32 [K][N] -> bf16 [N][K]) ----------
__global__ void cvt_wT_kernel(const float* __restrict__ W0, const float* __restrict__ W1,
                              const float* __restrict__ W2, const float* __restrict__ W3,
                              unsigned short* __restrict__ T0, unsigned short* __restrict__ T1,
                              unsigned short* __restrict__ T2, unsigned short* __restrict__ T3) {
  const float* W; unsigned short* T;
  switch (blockIdx.z) {
    case 0: W = W0; T = T0; break;
    case 1: W = W1; T = T1; break;
    case 2: W = W2; T = T2; break;
    default: W = W3; T = T3; break;
  }
  __shared__ float tile[32][33];
  int tx = threadIdx.x & 31, ty = threadIdx.x >> 5;
  int r0 = blockIdx.y * 32, c0 = blockIdx.x * 32;
#pragma unroll
  for (int i = 0; i < 4; i++) tile[ty + i * 8][tx] = W[(r0 + ty + i * 8) * 512 + c0 + tx];
  __syncthreads();
#pragma unroll
  for (int i = 0; i < 4; i++) T[(c0 + ty + i * 8) * 512 + r0 + tx] = f2bf(tile[tx][ty + i * 8]);
}

// ---------- GEMM core: C[128x128 tile] = A[M,K] * Bt[N,K]^T (+bias) ----------
// m97 structure: global_load_lds width-16 staging, XOR-swizzled k-granules
// (LDS[row][j] = global granule j^(row&3); read granule g at j=g^(row&3)),
// 2 barriers per BK=32 step, 4 waves (2x2), 4x4 16x16x32 MFMA frags per wave.
template <bool BF16OUT>
DEV void gemm_core(const unsigned short* __restrict__ A, int lda,
                   const unsigned short* __restrict__ Bt, int ldb,
                   const float* __restrict__ bias,
                   void* __restrict__ C, int ldc,
                   int kSteps, int koff,
                   unsigned short* As, unsigned short* Bs) {
  int tid = threadIdx.x;
  int lane = tid & 63, w = tid >> 6;
  int g = lane >> 4, r = lane & 15;
  int wr = w >> 1, wc = w & 1;
  int brow = blockIdx.x * 128, bcol = blockIdx.y * 128;
  f32x4 acc[4][4] = {};
  // staging geometry (per thread: 2 rows of A, 2 rows of B; 16B each)
  int srow0 = (w * 2 + 0) * 16 + (lane >> 2);
  int srow1 = (w * 2 + 1) * 16 + (lane >> 2);
  int sg = lane & 3;                       // dest granule (linear for gll)
  int sc0 = ((sg ^ (srow0 & 3)) * 8);      // swizzled source k-offset (elems)
  int sc1 = ((sg ^ (srow1 & 3)) * 8);
  const unsigned short* a0 = A + (size_t)(brow + srow0) * lda + koff + sc0;
  const unsigned short* a1 = A + (size_t)(brow + srow1) * lda + koff + sc1;
  const unsigned short* b0 = Bt + (size_t)(bcol + srow0) * ldb + koff + sc0;
  const unsigned short* b1 = Bt + (size_t)(bcol + srow1) * ldb + koff + sc1;
  unsigned short* la0 = &As[srow0 * 32 + sg * 8];
  unsigned short* la1 = &As[srow1 * 32 + sg * 8];
  unsigned short* lb0 = &Bs[srow0 * 32 + sg * 8];
  unsigned short* lb1 = &Bs[srow1 * 32 + sg * 8];
  // frag read offsets (swizzled): row%4 == r%4 for all m (wr*64+m*16 ≡ 0 mod 4)
  int fga = (g ^ (r & 3)) * 8;
  for (int ks = 0; ks < kSteps; ks++) {
    int kb = ks * 32;
    gll16(a0 + kb, la0);
    gll16(a1 + kb, la1);
    gll16(b0 + kb, lb0);
    gll16(b1 + kb, lb1);
    asm volatile("s_waitcnt vmcnt(0)" ::: "memory");
    __syncthreads();
    sh8 af[4], bfr[4];
#pragma unroll
    for (int m = 0; m < 4; m++) af[m] = *(const sh8*)&As[(wr * 64 + m * 16 + r) * 32 + fga];
#pragma unroll
    for (int n = 0; n < 4; n++) bfr[n] = *(const sh8*)&Bs[(wc * 64 + n * 16 + r) * 32 + fga];
#pragma unroll
    for (int m = 0; m < 4; m++)
#pragma unroll
      for (int n = 0; n < 4; n++) acc[m][n] = mfma16(af[m], bfr[n], acc[m][n]);
    __syncthreads();
  }
#pragma unroll
  for (int n = 0; n < 4; n++) {
    int col = bcol + wc * 64 + n * 16 + r;
    float bv = bias ? bias[col] : 0.f;
#pragma unroll
    for (int m = 0; m < 4; m++) {
      int row = brow + wr * 64 + m * 16 + g * 4;
#pragma unroll
      for (int i = 0; i < 4; i++) {
        float v = acc[m][n][i] + bv;
        if (BF16OUT) ((unsigned short*)C)[(size_t)(row + i) * ldc + col] = f2bf(v);
        else         ((float*)C)[(size_t)(row + i) * ldc + col] = v;
      }
    }
  }
}

// QKV batched wrapper (z selects weight/bias/output; all 512-stride)
__global__ __launch_bounds__(256, 2) void gemm_qkv_kernel(
    const unsigned short* __restrict__ A,
    const unsigned short* __restrict__ B0, const unsigned short* __restrict__ B1,
    const unsigned short* __restrict__ B2,
    const float* __restrict__ c0, const float* __restrict__ c1, const float* __restrict__ c2,
    unsigned short* __restrict__ C0, unsigned short* __restrict__ C1,
    unsigned short* __restrict__ C2) {
  __shared__ __align__(16) unsigned short As[128 * 32];
  __shared__ __align__(16) unsigned short Bs[128 * 32];
  const unsigned short* Bt; const float* bias; unsigned short* C;
  switch (blockIdx.z) {
    case 0: Bt = B0; bias = c0; C = C0; break;
    case 1: Bt = B1; bias = c1; C = C1; break;
    default: Bt = B2; bias = c2; C = C2; break;
  }
  gemm_core<true>(A, 512, Bt, 512, bias, C, 512, 16, 0, As, Bs);
}

// plain wrapper; z in {0,1} selects output buffer and k-offset (split-K)
template <bool BF16OUT>
__global__ __launch_bounds__(256, 2) void gemm_plain_kernel(
    const unsigned short* __restrict__ A, int lda,
    const unsigned short* __restrict__ Bt, int ldb,
    const float* __restrict__ bias,
    void* __restrict__ C0, void* __restrict__ C1, int ldc,
    int kSteps, int koffz) {
  __shared__ __align__(16) unsigned short As[128 * 32];
  __shared__ __align__(16) unsigned short Bs[128 * 32];
  void* C = blockIdx.z ? C1 : C0;
  gemm_core<BF16OUT>(A, lda, Bt, ldb, bias, C, ldc, kSteps, blockIdx.z * koffz, As, Bs);
}

// ---------- kernel 4: v [8192][512] -> vT [512][8192] (bf16) ----------
__global__ void transpose_v_kernel(const unsigned short* __restrict__ in, unsigned short* __restrict__ out) {
  __shared__ unsigned short tile[32][33];
  int tx = threadIdx.x & 31, ty = threadIdx.x >> 5;
  int r0 = blockIdx.y * 32, c0 = blockIdx.x * 32;
#pragma unroll
  for (int i = 0; i < 4; i++) tile[ty + i * 8][tx] = in[(size_t)(r0 + ty + i * 8) * 512 + c0 + tx];
  __syncthreads();
#pragma unroll
  for (int i = 0; i < 4; i++) out[(size_t)(c0 + ty + i * 8) * 8192 + r0 + tx] = tile[tx][ty + i * 8];
}

// ---------- row softmax on S [8192][8192] bf16, in place, normalized ----------
// one block per row; 256 threads x 32 elems; scale 1/sqrt(512) folded into exp2.
__global__ __launch_bounds__(256) void softmax_kernel(unsigned short* __restrict__ S) {
  __shared__ float red[8];
  const int tid = threadIdx.x, lane = tid & 63, w = tid >> 6;
  unsigned short* p = S + (size_t)blockIdx.x * 8192 + tid * 32;
  uint4 d[4];
#pragma unroll
  for (int j = 0; j < 4; j++) d[j] = ((const uint4*)p)[j];
  float v[32];
#pragma unroll
  for (int j = 0; j < 4; j++) {
    const unsigned* u = (const unsigned*)&d[j];
#pragma unroll
    for (int e = 0; e < 4; e++) {
      v[j * 8 + 2 * e]     = __uint_as_float(u[e] << 16);
      v[j * 8 + 2 * e + 1] = __uint_as_float(u[e] & 0xffff0000u);
    }
  }
  float m = v[0];
#pragma unroll
  for (int e = 1; e < 32; e++) m = fmaxf(m, v[e]);
  m = fmaxf(m, __shfl_xor(m, 1));
  m = fmaxf(m, __shfl_xor(m, 2));
  m = fmaxf(m, __shfl_xor(m, 4));
  m = fmaxf(m, __shfl_xor(m, 8));
  m = fmaxf(m, __shfl_xor(m, 16));
  m = fmaxf(m, __shfl_xor(m, 32));
  if (lane == 0) red[w] = m;
  __syncthreads();
  m = fmaxf(fmaxf(red[0], red[1]), fmaxf(red[2], red[3]));
  const float c = 0.04419417382415922f * 1.4426950408889634f;  // 1/sqrt(512)*log2e
  float pe[32], s = 0.f;
#pragma unroll
  for (int e = 0; e < 32; e++) {
    pe[e] = __builtin_amdgcn_exp2f((v[e] - m) * c);
    s += pe[e];
  }
  s += __shfl_xor(s, 1);
  s += __shfl_xor(s, 2);
  s += __shfl_xor(s, 4);
  s += __shfl_xor(s, 8);
  s += __shfl_xor(s, 16);
  s += __shfl_xor(s, 32);
  if (lane == 0) red[4 + w] = s;
  __syncthreads();
  float inv = 1.0f / (red[4] + red[5] + red[6] + red[7]);
#pragma unroll
  for (int j = 0; j < 4; j++) {
    unsigned o[4];
#pragma unroll
    for (int e = 0; e < 4; e++)
      o[e] = cvtpk(pe[j * 8 + 2 * e] * inv, pe[j * 8 + 2 * e + 1] * inv);
    ((uint4*)p)[j] = *(uint4*)o;
  }
}

// ---------- add two fp32 partials -> bf16 ----------
__global__ void addcvt_kernel(const float* __restrict__ a, const float* __restrict__ b,
                              unsigned short* __restrict__ o, int n4) {
  int i = blockIdx.x * blockDim.x + threadIdx.x;
  int stride = gridDim.x * blockDim.x;
  for (; i < n4; i += stride) {
    float4 va = ((const float4*)a)[i];
    float4 vb = ((const float4*)b)[i];
    ushort4 ov;
    ov.x = f2bf(va.x + vb.x); ov.y = f2bf(va.y + vb.y);
    ov.z = f2bf(va.z + vb.z); ov.w = f2bf(va.w + vb.w);
    ((ushort4*)o)[i] = ov;
  }
}

// ---------- fallback path: flash attention (round-3, passing) ----------
__global__ __launch_bounds__(256, 2) void flash_kernel(
    const unsigned short* __restrict__ Q, const unsigned short* __restrict__ Kb,
    const unsigned short* __restrict__ VT, float* __restrict__ Pout,
    float* __restrict__ ML, int nsLog2) {
  __shared__ __align__(16) unsigned short k_lds[2][32][512];
  __shared__ __align__(16) unsigned short p_lds[4][16][32];
  const int tid = threadIdx.x;
  const int lane = tid & 63, w = tid >> 6;
  const int g = lane >> 4, r = lane & 15;
  const int ns = 1 << nsLog2;
  const int split = blockIdx.x & (ns - 1);
  const int qblk = blockIdx.x >> nsLog2;
  const int qbase = qblk * 64 + w * 16;
  const int kvlen = 8192 >> nsLog2;
  const int kv0 = split * kvlen;
  const int nsteps = kvlen >> 5;
  sh8 qa[16];
#pragma unroll
  for (int dc = 0; dc < 16; dc++)
    qa[dc] = *(const sh8*)&Q[(qbase + r) * 512 + dc * 32 + g * 8];
  f32x4 acc[32] = {};
  float mrow = -1e30f, lrow = 0.f;
  const float K2r = 0.04419417382415922f * 1.4426950408889634f;
#pragma unroll
  for (int ii = 0; ii < 8; ii++) {
    int row = w * 8 + ii;
    gll16(Kb + (size_t)(kv0 + row) * 512 + (size_t)((lane ^ ii) * 8), &k_lds[0][row][0]);
  }
  int cur = 0;
  const int swz = (r & 7) * 8;
  for (int s = 0; s < nsteps; s++) {
    const int kvrow0 = kv0 + s * 32;
    asm volatile("s_waitcnt vmcnt(0)" ::: "memory");
    __syncthreads();
    if (s + 1 < nsteps) {
#pragma unroll
      for (int ii = 0; ii < 8; ii++) {
        int row = w * 8 + ii;
        gll16(Kb + (size_t)(kvrow0 + 32 + row) * 512 + (size_t)((lane ^ ii) * 8),
              &k_lds[cur ^ 1][row][0]);
      }
    }
    f32x4 sA0 = {0.f, 0.f, 0.f, 0.f};
    f32x4 sA1 = {0.f, 0.f, 0.f, 0.f};
#pragma unroll
    for (int dc = 0; dc < 16; dc++) {
      int co = (dc * 32 + g * 8) ^ swz;
      sh8 kf0 = *(const sh8*)&k_lds[cur][r][co];
      sh8 kf1 = *(const sh8*)&k_lds[cur][16 + r][co];
      sA0 = mfma16(kf0, qa[dc], sA0);
      sA1 = mfma16(kf1, qa[dc], sA1);
    }
    float rmax = fmaxf(fmaxf(fmaxf(sA0[0], sA0[1]), fmaxf(sA0[2], sA0[3])),
                       fmaxf(fmaxf(sA1[0], sA1[1]), fmaxf(sA1[2], sA1[3])));
    rmax = fmaxf(rmax, __shfl_xor(rmax, 16));
    rmax = fmaxf(rmax, __shfl_xor(rmax, 32));
    float tmax = rmax * K2r;
    if (__any(tmax > mrow + 4.0f)) {
      float mn = fmaxf(mrow, tmax);
      float corr = __builtin_amdgcn_exp2f(mrow - mn);
      mrow = mn;
      lrow *= corr;
      f32x4 cv;
      cv[0] = __shfl(corr, 4 * g + 0);
      cv[1] = __shfl(corr, 4 * g + 1);
      cv[2] = __shfl(corr, 4 * g + 2);
      cv[3] = __shfl(corr, 4 * g + 3);
#pragma unroll
      for (int dt = 0; dt < 32; dt++) acc[dt] *= cv;
    }
    float p0 = __builtin_amdgcn_exp2f(fmaf(sA0[0], K2r, -mrow));
    float p1 = __builtin_amdgcn_exp2f(fmaf(sA0[1], K2r, -mrow));
    float p2 = __builtin_amdgcn_exp2f(fmaf(sA0[2], K2r, -mrow));
    float p3 = __builtin_amdgcn_exp2f(fmaf(sA0[3], K2r, -mrow));
    float p4 = __builtin_amdgcn_exp2f(fmaf(sA1[0], K2r, -mrow));
    float p5 = __builtin_amdgcn_exp2f(fmaf(sA1[1], K2r, -mrow));
    float p6 = __builtin_amdgcn_exp2f(fmaf(sA1[2], K2r, -mrow));
    float p7 = __builtin_amdgcn_exp2f(fmaf(sA1[3], K2r, -mrow));
    float ps = ((p0 + p1) + (p2 + p3)) + ((p4 + p5) + (p6 + p7));
    ps += __shfl_xor(ps, 16);
    ps += __shfl_xor(ps, 32);
    lrow += ps;
    uint2 w0, w1;
    w0.x = cvtpk(p0, p1); w0.y = cvtpk(p2, p3);
    w1.x = cvtpk(p4, p5); w1.y = cvtpk(p6, p7);
    *(uint2*)&p_lds[w][r][4 * g] = w0;
    *(uint2*)&p_lds[w][r][16 + 4 * g] = w1;
    sh8 pf = *(const sh8*)&p_lds[w][r][8 * g];
#pragma unroll
    for (int dt = 0; dt < 32; dt++) {
      sh8 vf = *(const sh8*)&VT[(dt * 16 + r) * 8192 + kvrow0 + g * 8];
      acc[dt] = mfma16(pf, vf, acc[dt]);
    }
    cur ^= 1;
  }
  float* P = Pout + (size_t)split * 4194304;
#pragma unroll
  for (int dt = 0; dt < 32; dt++)
#pragma unroll
    for (int i = 0; i < 4; i++)
      P[(qbase + 4 * g + i) * 512 + dt * 16 + r] = acc[dt][i];
  if (g == 0) {
    ML[(split * 2 + 0) * 8192 + qbase + r] = mrow;
    ML[(split * 2 + 1) * 8192 + qbase + r] = lrow;
  }
}

template <int NS>
__global__ void combine_kernel(const float* __restrict__ Pp, const float* __restrict__ ML,
                               unsigned short* __restrict__ att) {
  int idx = blockIdx.x * blockDim.x + threadIdx.x;
  int stride = gridDim.x * blockDim.x;
  for (int i4 = idx; i4 < 8192 * 512 / 4; i4 += stride) {
    int row = i4 >> 7;
    float m[NS], l[NS], e[NS];
    float mm = -1e30f;
#pragma unroll
    for (int s2 = 0; s2 < NS; s2++) {
      m[s2] = ML[(s2 * 2 + 0) * 8192 + row];
      l[s2] = ML[(s2 * 2 + 1) * 8192 + row];
      mm = fmaxf(mm, m[s2]);
    }
    float den = 0.f;
#pragma unroll
    for (int s2 = 0; s2 < NS; s2++) {
      e[s2] = __builtin_amdgcn_exp2f(m[s2] - mm);
      den += l[s2] * e[s2];
    }
    float inv = 1.0f / den;
    float ox = 0.f, oy = 0.f, oz = 0.f, ow = 0.f;
#pragma unroll
    for (int s2 = 0; s2 < NS; s2++) {
      float4 a = ((const float4*)(Pp + (size_t)s2 * 4194304))[i4];
      ox += a.x * e[s2]; oy += a.y * e[s2]; oz += a.z * e[s2]; ow += a.w * e[s2];
    }
    ushort4 ov;
    ov.x = f2bf(ox * inv); ov.y = f2bf(oy * inv);
    ov.z = f2bf(oz * inv); ov.w = f2bf(ow * inv);
    ((ushort4*)att)[i4] = ov;
  }
}

// ---------- launch ----------
extern "C" void kernel_launch(void* const* d_in, const int* in_sizes, int n_in,
                              void* d_out, int out_size, void* d_ws, size_t ws_size,
                              hipStream_t stream) {
  const float* x  = (const float*)d_in[0];
  const float* Wq = (const float*)d_in[1];
  const float* bq = (const float*)d_in[2];
  const float* Wk = (const float*)d_in[3];
  const float* bk = (const float*)d_in[4];
  const float* Wv = (const float*)d_in[5];
  const float* bv = (const float*)d_in[6];
  const float* Wo = (const float*)d_in[7];
  const float* bo = (const float*)d_in[8];
  char* ws = (char*)d_ws;

  if (ws_size >= 161480704ull) {
    // ---- Path A: two-pass GEMM attention ----
    // layout: S [0,134.2MB) with xb@0(8MB), vb@8MB(8MB), att@0 overlaid
    unsigned short* S   = (unsigned short*)(ws + 0);
    unsigned short* xb  = (unsigned short*)(ws + 0);
    unsigned short* vb  = (unsigned short*)(ws + 8388608);
    unsigned short* att = (unsigned short*)(ws + 0);
    unsigned short* qb  = (unsigned short*)(ws + 134217728);
    unsigned short* kb  = (unsigned short*)(ws + 142606336);
    unsigned short* vtb = (unsigned short*)(ws + 150994944);
    unsigned short* wqT = (unsigned short*)(ws + 159383552);
    unsigned short* wkT = (unsigned short*)(ws + 159907840);
    unsigned short* wvT = (unsigned short*)(ws + 160432128);
    unsigned short* woT = (unsigned short*)(ws + 160956416);
    float* P0 = (float*)qb;          // 16 MiB spans qb+kb (both dead by PV)
    float* P1 = (float*)d_out;       // 16 MiB, overwritten by O-proj after

    cvt_x_kernel<<<2048, 256, 0, stream>>>(x, xb, 8192 * 512 / 4);
    cvt_wT_kernel<<<dim3(16, 16, 4), 256, 0, stream>>>(Wq, Wk, Wv, Wo, wqT, wkT, wvT, woT);
    gemm_qkv_kernel<<<dim3(64, 4, 3), 256, 0, stream>>>(
        xb, wqT, wkT, wvT, bq, bk, bv, qb, kb, vb);
    transpose_v_kernel<<<dim3(16, 256), 256, 0, stream>>>(vb, vtb);
    // S = q @ k^T (raw scores, bf16)
    gemm_plain_kernel<true><<<dim3(64, 64, 1), 256, 0, stream>>>(
        qb, 512, kb, 512, nullptr, S, nullptr, 8192, 16, 0);
    softmax_kernel<<<8192, 256, 0, stream>>>(S);
    // PV split-K=2: P0 = S[:, :4096] @ V[:4096], P1 = S[:, 4096:] @ V[4096:]
    gemm_plain_kernel<false><<<dim3(64, 4, 2), 256, 0, stream>>>(
        S, 8192, vtb, 8192, nullptr, P0, P1, 512, 128, 4096);
    addcvt_kernel<<<2048, 256, 0, stream>>>(P0, P1, att, 8192 * 512 / 4);
    gemm_plain_kernel<false><<<dim3(64, 4, 1), 256, 0, stream>>>(
        att, 512, woT, 512, bo, d_out, nullptr, 512, 16, 0);
  } else {
    // ---- Path B: flash fallback (round-3) ----
    unsigned short* xb  = (unsigned short*)(ws + 0);
    unsigned short* qb  = (unsigned short*)(ws + 8388608);
    unsigned short* kb  = (unsigned short*)(ws + 16777216);
    unsigned short* vb  = (unsigned short*)(ws + 25165824);
    unsigned short* vtb = (unsigned short*)(ws + 33554432);
    unsigned short* att = (unsigned short*)(ws + 41943040);
    unsigned short* wqT = (unsigned short*)(ws + 50331648);
    unsigned short* wkT = (unsigned short*)(ws + 50855936);
    unsigned short* wvT = (unsigned short*)(ws + 51380224);
    unsigned short* woT = (unsigned short*)(ws + 51904512);
    float* ml   = (float*)(ws + 52428800);
    float* part = (float*)(ws + 52690944);
    int nsLog2 = (ws_size >= 119900000ull) ? 2 : 1;
    int NS = 1 << nsLog2;

    cvt_x_kernel<<<2048, 256, 0, stream>>>(x, xb, 8192 * 512 / 4);
    cvt_wT_kernel<<<dim3(16, 16, 4), 256, 0, stream>>>(Wq, Wk, Wv, Wo, wqT, wkT, wvT, woT);
    gemm_qkv_kernel<<<dim3(64, 4, 3), 256, 0, stream>>>(
        xb, wqT, wkT, wvT, bq, bk, bv, qb, kb, vb);
    transpose_v_kernel<<<dim3(16, 256), 256, 0, stream>>>(vb, vtb);
    flash_kernel<<<128 * NS, 256, 0, stream>>>(qb, kb, vtb, part, ml, nsLog2);
    if (NS == 4) combine_kernel<4><<<1024, 256, 0, stream>>>(part, ml, att);
    else         combine_kernel<2><<<1024, 256, 0, stream>>>(part, ml, att);
    gemm_plain_kernel<false><<<dim3(64, 4, 1), 256, 0, stream>>>(
        att, 512, woT, 512, bo, d_out, nullptr, 512, 16, 0);
  }
}

// Round 5
// 263.844 us; speedup vs baseline: 2.5340x; 1.2054x over previous
//
#include <hip/hip_runtime.h>

// ---------- common ----------
typedef short sh8 __attribute__((ext_vector_type(8)));
typedef float f32x4 __attribute__((ext_vector_type(4)));

#define DEV __device__ __forceinline__

DEV f32x4 mfma16(sh8 a, sh8 b, f32x4 c) {
  return __builtin_amdgcn_mfma_f32_16x16x32_bf16(a, b, c, 0, 0, 0);
}

DEV unsigned short f2bf(float f) {
  unsigned u = __float_as_uint(f);
  u = u + 0x7FFFu + ((u >> 16) & 1u);   // RNE
  return (unsigned short)(u >> 16);
}

DEV unsigned cvtpk(float lo, float hi) {
  unsigned r;
  asm("v_cvt_pk_bf16_f32 %0, %1, %2" : "=v"(r) : "v"(lo), "v"(hi));
  return r;
}

DEV void gll16(const void* g, void* l) {
  __builtin_amdgcn_global_load_lds(
      (const __attribute__((address_space(1))) unsigned int*)g,
      (__attribute__((address_space(3))) unsigned int*)l, 16, 0, 0);
}

// ---------- kernel: x fp32 -> bf16 ----------
__global__ void cvt_x_kernel(const float* __restrict__ x, unsigned short* __restrict__ xb, int n4) {
  int i = blockIdx.x * blockDim.x + threadIdx.x;
  int stride = gridDim.x * blockDim.x;
  for (; i < n4; i += stride) {
    float4 v = ((const float4*)x)[i];
    ushort4 o;
    o.x = f2bf(v.x); o.y = f2bf(v.y); o.z = f2bf(v.z); o.w = f2bf(v.w);
    ((ushort4*)xb)[i] = o;
  }
}

// ---------- kernel: weight transpose + cvt (512x512 fp32 [K][N] -> bf16 [N][K]) ----------
__global__ void cvt_wT_kernel(const float* __restrict__ W0, const float* __restrict__ W1,
                              const float* __restrict__ W2, const float* __restrict__ W3,
                              unsigned short* __restrict__ T0, unsigned short* __restrict__ T1,
                              unsigned short* __restrict__ T2, unsigned short* __restrict__ T3) {
  const float* W; unsigned short* T;
  switch (blockIdx.z) {
    case 0: W = W0; T = T0; break;
    case 1: W = W1; T = T1; break;
    case 2: W = W2; T = T2; break;
    default: W = W3; T = T3; break;
  }
  __shared__ float tile[32][33];
  int tx = threadIdx.x & 31, ty = threadIdx.x >> 5;
  int r0 = blockIdx.y * 32, c0 = blockIdx.x * 32;
#pragma unroll
  for (int i = 0; i < 4; i++) tile[ty + i * 8][tx] = W[(r0 + ty + i * 8) * 512 + c0 + tx];
  __syncthreads();
#pragma unroll
  for (int i = 0; i < 4; i++) T[(c0 + ty + i * 8) * 512 + r0 + tx] = f2bf(tile[tx][ty + i * 8]);
}

// ---------- GEMM core (BK=64) ----------
// 128x128 tile, 4 waves (2x2), per step: 8x gll16 stage (XOR-swizzled src,
// linear dest), 2 sub-K of 16 MFMA. MODE: 0 = fp32 direct store (+bias),
// 1 = bf16 via LDS coalesced store (+bias), 2 = exp2(acc*c) bf16 via LDS
// coalesced store + per-block row-sum partials to lpart.
template <int MODE>
DEV void gemm_core(const unsigned short* __restrict__ A, int lda,
                   const unsigned short* __restrict__ Bt, int ldb,
                   const float* __restrict__ bias, void* __restrict__ Cv, int ldc,
                   int kSteps, int koff, int brow, int bcol,
                   float* __restrict__ lpart, unsigned short* smem) {
  unsigned short* As = smem;
  unsigned short* Bs = smem + 8192;
  const int tid = threadIdx.x, lane = tid & 63, w = tid >> 6;
  const int g = lane >> 4, r = lane & 15;
  const int wr = w >> 1, wc = w & 1;
  const int rA = w * 8 + (lane >> 3);           // staging row (cc=0)
  const int sgl = lane & 7;                     // dest granule (linear)
  const int scol = ((sgl ^ (lane >> 3)) * 8);   // pre-swizzled src col
  const unsigned short* aP = A + (size_t)(brow + rA) * lda + koff + scol;
  const unsigned short* bP = Bt + (size_t)(bcol + rA) * ldb + koff + scol;
  unsigned short* lA = As + rA * 64 + sgl * 8;
  unsigned short* lB = Bs + rA * 64 + sgl * 8;
  f32x4 acc[4][4] = {};
  const int fr = r & 7;
  for (int ks = 0; ks < kSteps; ks++) {
    const size_t ko = (size_t)ks * 64;
#pragma unroll
    for (int cc = 0; cc < 4; cc++) gll16(aP + (size_t)cc * 32 * lda + ko, lA + cc * 32 * 64);
#pragma unroll
    for (int cc = 0; cc < 4; cc++) gll16(bP + (size_t)cc * 32 * ldb + ko, lB + cc * 32 * 64);
    asm volatile("s_waitcnt vmcnt(0)" ::: "memory");
    __syncthreads();
#pragma unroll
    for (int kk = 0; kk < 2; kk++) {
      sh8 af[4], bfr[4];
#pragma unroll
      for (int m = 0; m < 4; m++)
        af[m] = *(const sh8*)&As[(wr * 64 + m * 16 + r) * 64 + (((kk * 4 + g) ^ fr) * 8)];
#pragma unroll
      for (int n = 0; n < 4; n++)
        bfr[n] = *(const sh8*)&Bs[(wc * 64 + n * 16 + r) * 64 + (((kk * 4 + g) ^ fr) * 8)];
#pragma unroll
      for (int m = 0; m < 4; m++)
#pragma unroll
        for (int n = 0; n < 4; n++) acc[m][n] = mfma16(af[m], bfr[n], acc[m][n]);
    }
    __syncthreads();
  }
  const float K2c = 0.04419417382415922f * 1.4426950408889634f;  // 1/sqrt(512)*log2e
  if (MODE == 0) {
#pragma unroll
    for (int n = 0; n < 4; n++) {
      int col = bcol + wc * 64 + n * 16 + r;
      float bv = bias ? bias[col] : 0.f;
#pragma unroll
      for (int m = 0; m < 4; m++) {
        int row = brow + wr * 64 + m * 16 + g * 4;
#pragma unroll
        for (int i = 0; i < 4; i++)
          ((float*)Cv)[(size_t)(row + i) * ldc + col] = acc[m][n][i] + bv;
      }
    }
  } else {
    // restage C-tile in LDS (stride 132 -> conflict-friendly), coalesced out
#pragma unroll
    for (int m = 0; m < 4; m++) {
      float rs0 = 0.f, rs1 = 0.f, rs2 = 0.f, rs3 = 0.f;
#pragma unroll
      for (int n = 0; n < 4; n++) {
        int coll = wc * 64 + n * 16 + r;
        float bv = (MODE == 1 && bias) ? bias[bcol + coll] : 0.f;
        float v0 = acc[m][n][0] + bv, v1 = acc[m][n][1] + bv;
        float v2 = acc[m][n][2] + bv, v3 = acc[m][n][3] + bv;
        if (MODE == 2) {
          v0 = __builtin_amdgcn_exp2f(v0 * K2c); rs0 += v0;
          v1 = __builtin_amdgcn_exp2f(v1 * K2c); rs1 += v1;
          v2 = __builtin_amdgcn_exp2f(v2 * K2c); rs2 += v2;
          v3 = __builtin_amdgcn_exp2f(v3 * K2c); rs3 += v3;
        }
        int rb = (wr * 64 + m * 16 + g * 4) * 132 + coll;
        smem[rb] = f2bf(v0);
        smem[rb + 132] = f2bf(v1);
        smem[rb + 264] = f2bf(v2);
        smem[rb + 396] = f2bf(v3);
      }
      if (MODE == 2) {
        float rs[4] = {rs0, rs1, rs2, rs3};
#pragma unroll
        for (int i = 0; i < 4; i++) {
          float t = rs[i];
          t += __shfl_xor(t, 1); t += __shfl_xor(t, 2);
          t += __shfl_xor(t, 4); t += __shfl_xor(t, 8);
          if (r == 0)
            lpart[(size_t)((bcol >> 7) * 2 + wc) * 8192 + brow + wr * 64 + m * 16 + g * 4 + i] = t;
        }
      }
    }
    __syncthreads();
    unsigned short* C = (unsigned short*)Cv;
#pragma unroll
    for (int j = 0; j < 8; j++) {
      int row = w * 32 + j * 4 + (lane >> 4);
      int colb = (lane & 15) * 8;
      uint4 v = *(const uint4*)&smem[row * 132 + colb];
      *(uint4*)&C[(size_t)(brow + row) * ldc + bcol + colb] = v;
    }
  }
}

// ---------- GEMM wrappers ----------
__global__ __launch_bounds__(256, 2) void gemm_qkv_kernel(
    const unsigned short* __restrict__ A,
    const unsigned short* __restrict__ B0, const unsigned short* __restrict__ B1,
    const unsigned short* __restrict__ B2,
    const float* __restrict__ c0, const float* __restrict__ c1, const float* __restrict__ c2,
    unsigned short* __restrict__ C0, unsigned short* __restrict__ C1,
    unsigned short* __restrict__ C2) {
  __shared__ __align__(16) unsigned short smem[16896];
  const unsigned short* Bt; const float* bias; unsigned short* C;
  switch (blockIdx.z) {
    case 0: Bt = B0; bias = c0; C = C0; break;
    case 1: Bt = B1; bias = c1; C = C1; break;
    default: Bt = B2; bias = c2; C = C2; break;
  }
  gemm_core<1>(A, 512, Bt, 512, bias, C, 512, 8, 0,
               blockIdx.x * 128, blockIdx.y * 128, nullptr, smem);
}

__global__ __launch_bounds__(256, 2) void gemm_u_kernel(
    const unsigned short* __restrict__ Q, const unsigned short* __restrict__ Kb,
    unsigned short* __restrict__ U, float* __restrict__ lpart) {
  __shared__ __align__(16) unsigned short smem[16896];
  gemm_core<2>(Q, 512, Kb, 512, nullptr, U, 8192, 8, 0,
               blockIdx.x * 128, blockIdx.y * 128, lpart, smem);
}

__global__ __launch_bounds__(256, 2) void gemm_s_kernel(
    const unsigned short* __restrict__ Q, const unsigned short* __restrict__ Kb,
    unsigned short* __restrict__ S) {
  __shared__ __align__(16) unsigned short smem[16896];
  gemm_core<1>(Q, 512, Kb, 512, nullptr, S, 8192, 8, 0,
               blockIdx.x * 128, blockIdx.y * 128, nullptr, smem);
}

__global__ __launch_bounds__(256, 2) void gemm_pv_kernel(
    const unsigned short* __restrict__ U, const unsigned short* __restrict__ VT,
    float* __restrict__ P0, float* __restrict__ P1) {
  __shared__ __align__(16) unsigned short smem[16896];
  float* P = blockIdx.z ? P1 : P0;
  gemm_core<0>(U, 8192, VT, 8192, nullptr, P, 512, 64, blockIdx.z * 4096,
               blockIdx.y * 128, blockIdx.x * 128, nullptr, smem);
}

__global__ __launch_bounds__(256, 2) void gemm_o_kernel(
    const unsigned short* __restrict__ att, const unsigned short* __restrict__ woT,
    const float* __restrict__ bo, float* __restrict__ out) {
  __shared__ __align__(16) unsigned short smem[16896];
  gemm_core<0>(att, 512, woT, 512, bo, out, 512, 8, 0,
               blockIdx.x * 128, blockIdx.y * 128, nullptr, smem);
}

// ---------- kernel: v [8192][512] -> vT [512][8192] (bf16) ----------
__global__ void transpose_v_kernel(const unsigned short* __restrict__ in, unsigned short* __restrict__ out) {
  __shared__ unsigned short tile[32][33];
  int tx = threadIdx.x & 31, ty = threadIdx.x >> 5;
  int r0 = blockIdx.y * 32, c0 = blockIdx.x * 32;
#pragma unroll
  for (int i = 0; i < 4; i++) tile[ty + i * 8][tx] = in[(size_t)(r0 + ty + i * 8) * 512 + c0 + tx];
  __syncthreads();
#pragma unroll
  for (int i = 0; i < 4; i++) out[(size_t)(c0 + ty + i * 8) * 8192 + r0 + tx] = tile[tx][ty + i * 8];
}

// ---------- combine row-sum partials -> 1/l ----------
__global__ void combine_l_kernel(const float* __restrict__ lpart, float* __restrict__ linv) {
  int row = blockIdx.x * 256 + threadIdx.x;
  float s = 0.f;
#pragma unroll 8
  for (int j = 0; j < 128; j++) s += lpart[(size_t)j * 8192 + row];
  linv[row] = 1.0f / s;
}

// ---------- add two fp32 partials (optionally * linv[row]) -> bf16 ----------
template <bool NORM>
__global__ void addcvt_kernel(const float* __restrict__ a, const float* __restrict__ b,
                              const float* __restrict__ linv,
                              unsigned short* __restrict__ o, int n4) {
  int i = blockIdx.x * blockDim.x + threadIdx.x;
  int stride = gridDim.x * blockDim.x;
  for (; i < n4; i += stride) {
    float inv = NORM ? linv[i >> 7] : 1.0f;
    float4 va = ((const float4*)a)[i];
    float4 vb = ((const float4*)b)[i];
    ushort4 ov;
    ov.x = f2bf((va.x + vb.x) * inv); ov.y = f2bf((va.y + vb.y) * inv);
    ov.z = f2bf((va.z + vb.z) * inv); ov.w = f2bf((va.w + vb.w) * inv);
    ((ushort4*)o)[i] = ov;
  }
}

// ---------- fallback: row softmax on S [8192][8192] bf16, in place ----------
__global__ __launch_bounds__(256) void softmax_kernel(unsigned short* __restrict__ S) {
  __shared__ float red[8];
  const int tid = threadIdx.x, lane = tid & 63, w = tid >> 6;
  unsigned short* p = S + (size_t)blockIdx.x * 8192 + tid * 32;
  uint4 d[4];
#pragma unroll
  for (int j = 0; j < 4; j++) d[j] = ((const uint4*)p)[j];
  float v[32];
#pragma unroll
  for (int j = 0; j < 4; j++) {
    const unsigned* u = (const unsigned*)&d[j];
#pragma unroll
    for (int e = 0; e < 4; e++) {
      v[j * 8 + 2 * e]     = __uint_as_float(u[e] << 16);
      v[j * 8 + 2 * e + 1] = __uint_as_float(u[e] & 0xffff0000u);
    }
  }
  float m = v[0];
#pragma unroll
  for (int e = 1; e < 32; e++) m = fmaxf(m, v[e]);
  m = fmaxf(m, __shfl_xor(m, 1)); m = fmaxf(m, __shfl_xor(m, 2));
  m = fmaxf(m, __shfl_xor(m, 4)); m = fmaxf(m, __shfl_xor(m, 8));
  m = fmaxf(m, __shfl_xor(m, 16)); m = fmaxf(m, __shfl_xor(m, 32));
  if (lane == 0) red[w] = m;
  __syncthreads();
  m = fmaxf(fmaxf(red[0], red[1]), fmaxf(red[2], red[3]));
  const float c = 0.04419417382415922f * 1.4426950408889634f;
  float pe[32], s = 0.f;
#pragma unroll
  for (int e = 0; e < 32; e++) {
    pe[e] = __builtin_amdgcn_exp2f((v[e] - m) * c);
    s += pe[e];
  }
  s += __shfl_xor(s, 1); s += __shfl_xor(s, 2); s += __shfl_xor(s, 4);
  s += __shfl_xor(s, 8); s += __shfl_xor(s, 16); s += __shfl_xor(s, 32);
  if (lane == 0) red[4 + w] = s;
  __syncthreads();
  float inv = 1.0f / (red[4] + red[5] + red[6] + red[7]);
#pragma unroll
  for (int j = 0; j < 4; j++) {
    unsigned o[4];
#pragma unroll
    for (int e = 0; e < 4; e++)
      o[e] = cvtpk(pe[j * 8 + 2 * e] * inv, pe[j * 8 + 2 * e + 1] * inv);
    ((uint4*)p)[j] = *(uint4*)o;
  }
}

// ---------- deep fallback: flash attention ----------
__global__ __launch_bounds__(256, 2) void flash_kernel(
    const unsigned short* __restrict__ Q, const unsigned short* __restrict__ Kb,
    const unsigned short* __restrict__ VT, float* __restrict__ Pout,
    float* __restrict__ ML, int nsLog2) {
  __shared__ __align__(16) unsigned short k_lds[2][32][512];
  __shared__ __align__(16) unsigned short p_lds[4][16][32];
  const int tid = threadIdx.x;
  const int lane = tid & 63, w = tid >> 6;
  const int g = lane >> 4, r = lane & 15;
  const int ns = 1 << nsLog2;
  const int split = blockIdx.x & (ns - 1);
  const int qblk = blockIdx.x >> nsLog2;
  const int qbase = qblk * 64 + w * 16;
  const int kvlen = 8192 >> nsLog2;
  const int kv0 = split * kvlen;
  const int nsteps = kvlen >> 5;
  sh8 qa[16];
#pragma unroll
  for (int dc = 0; dc < 16; dc++)
    qa[dc] = *(const sh8*)&Q[(qbase + r) * 512 + dc * 32 + g * 8];
  f32x4 acc[32] = {};
  float mrow = -1e30f, lrow = 0.f;
  const float K2r = 0.04419417382415922f * 1.4426950408889634f;
#pragma unroll
  for (int ii = 0; ii < 8; ii++) {
    int row = w * 8 + ii;
    gll16(Kb + (size_t)(kv0 + row) * 512 + (size_t)((lane ^ ii) * 8), &k_lds[0][row][0]);
  }
  int cur = 0;
  const int swz = (r & 7) * 8;
  for (int s = 0; s < nsteps; s++) {
    const int kvrow0 = kv0 + s * 32;
    asm volatile("s_waitcnt vmcnt(0)" ::: "memory");
    __syncthreads();
    if (s + 1 < nsteps) {
#pragma unroll
      for (int ii = 0; ii < 8; ii++) {
        int row = w * 8 + ii;
        gll16(Kb + (size_t)(kvrow0 + 32 + row) * 512 + (size_t)((lane ^ ii) * 8),
              &k_lds[cur ^ 1][row][0]);
      }
    }
    f32x4 sA0 = {0.f, 0.f, 0.f, 0.f};
    f32x4 sA1 = {0.f, 0.f, 0.f, 0.f};
#pragma unroll
    for (int dc = 0; dc < 16; dc++) {
      int co = (dc * 32 + g * 8) ^ swz;
      sh8 kf0 = *(const sh8*)&k_lds[cur][r][co];
      sh8 kf1 = *(const sh8*)&k_lds[cur][16 + r][co];
      sA0 = mfma16(kf0, qa[dc], sA0);
      sA1 = mfma16(kf1, qa[dc], sA1);
    }
    float rmax = fmaxf(fmaxf(fmaxf(sA0[0], sA0[1]), fmaxf(sA0[2], sA0[3])),
                       fmaxf(fmaxf(sA1[0], sA1[1]), fmaxf(sA1[2], sA1[3])));
    rmax = fmaxf(rmax, __shfl_xor(rmax, 16));
    rmax = fmaxf(rmax, __shfl_xor(rmax, 32));
    float tmax = rmax * K2r;
    if (__any(tmax > mrow + 4.0f)) {
      float mn = fmaxf(mrow, tmax);
      float corr = __builtin_amdgcn_exp2f(mrow - mn);
      mrow = mn;
      lrow *= corr;
      f32x4 cv;
      cv[0] = __shfl(corr, 4 * g + 0);
      cv[1] = __shfl(corr, 4 * g + 1);
      cv[2] = __shfl(corr, 4 * g + 2);
      cv[3] = __shfl(corr, 4 * g + 3);
#pragma unroll
      for (int dt = 0; dt < 32; dt++) acc[dt] *= cv;
    }
    float p0 = __builtin_amdgcn_exp2f(fmaf(sA0[0], K2r, -mrow));
    float p1 = __builtin_amdgcn_exp2f(fmaf(sA0[1], K2r, -mrow));
    float p2 = __builtin_amdgcn_exp2f(fmaf(sA0[2], K2r, -mrow));
    float p3 = __builtin_amdgcn_exp2f(fmaf(sA0[3], K2r, -mrow));
    float p4 = __builtin_amdgcn_exp2f(fmaf(sA1[0], K2r, -mrow));
    float p5 = __builtin_amdgcn_exp2f(fmaf(sA1[1], K2r, -mrow));
    float p6 = __builtin_amdgcn_exp2f(fmaf(sA1[2], K2r, -mrow));
    float p7 = __builtin_amdgcn_exp2f(fmaf(sA1[3], K2r, -mrow));
    float ps = ((p0 + p1) + (p2 + p3)) + ((p4 + p5) + (p6 + p7));
    ps += __shfl_xor(ps, 16);
    ps += __shfl_xor(ps, 32);
    lrow += ps;
    uint2 w0, w1;
    w0.x = cvtpk(p0, p1); w0.y = cvtpk(p2, p3);
    w1.x = cvtpk(p4, p5); w1.y = cvtpk(p6, p7);
    *(uint2*)&p_lds[w][r][4 * g] = w0;
    *(uint2*)&p_lds[w][r][16 + 4 * g] = w1;
    sh8 pf = *(const sh8*)&p_lds[w][r][8 * g];
#pragma unroll
    for (int dt = 0; dt < 32; dt++) {
      sh8 vf = *(const sh8*)&VT[(dt * 16 + r) * 8192 + kvrow0 + g * 8];
      acc[dt] = mfma16(pf, vf, acc[dt]);
    }
    cur ^= 1;
  }
  float* P = Pout + (size_t)split * 4194304;
#pragma unroll
  for (int dt = 0; dt < 32; dt++)
#pragma unroll
    for (int i = 0; i < 4; i++)
      P[(qbase + 4 * g + i) * 512 + dt * 16 + r] = acc[dt][i];
  if (g == 0) {
    ML[(split * 2 + 0) * 8192 + qbase + r] = mrow;
    ML[(split * 2 + 1) * 8192 + qbase + r] = lrow;
  }
}

template <int NS>
__global__ void combine_kernel(const float* __restrict__ Pp, const float* __restrict__ ML,
                               unsigned short* __restrict__ att) {
  int idx = blockIdx.x * blockDim.x + threadIdx.x;
  int stride = gridDim.x * blockDim.x;
  for (int i4 = idx; i4 < 8192 * 512 / 4; i4 += stride) {
    int row = i4 >> 7;
    float m[NS], l[NS], e[NS];
    float mm = -1e30f;
#pragma unroll
    for (int s2 = 0; s2 < NS; s2++) {
      m[s2] = ML[(s2 * 2 + 0) * 8192 + row];
      l[s2] = ML[(s2 * 2 + 1) * 8192 + row];
      mm = fmaxf(mm, m[s2]);
    }
    float den = 0.f;
#pragma unroll
    for (int s2 = 0; s2 < NS; s2++) {
      e[s2] = __builtin_amdgcn_exp2f(m[s2] - mm);
      den += l[s2] * e[s2];
    }
    float inv = 1.0f / den;
    float ox = 0.f, oy = 0.f, oz = 0.f, ow = 0.f;
#pragma unroll
    for (int s2 = 0; s2 < NS; s2++) {
      float4 a = ((const float4*)(Pp + (size_t)s2 * 4194304))[i4];
      ox += a.x * e[s2]; oy += a.y * e[s2]; oz += a.z * e[s2]; ow += a.w * e[s2];
    }
    ushort4 ov;
    ov.x = f2bf(ox * inv); ov.y = f2bf(oy * inv);
    ov.z = f2bf(oz * inv); ov.w = f2bf(ow * inv);
    ((ushort4*)att)[i4] = ov;
  }
}

// ---------- launch ----------
extern "C" void kernel_launch(void* const* d_in, const int* in_sizes, int n_in,
                              void* d_out, int out_size, void* d_ws, size_t ws_size,
                              hipStream_t stream) {
  const float* x  = (const float*)d_in[0];
  const float* Wq = (const float*)d_in[1];
  const float* bq = (const float*)d_in[2];
  const float* Wk = (const float*)d_in[3];
  const float* bk = (const float*)d_in[4];
  const float* Wv = (const float*)d_in[5];
  const float* bv = (const float*)d_in[6];
  const float* Wo = (const float*)d_in[7];
  const float* bo = (const float*)d_in[8];
  char* ws = (char*)d_ws;

  if (ws_size >= 165707776ull) {
    // ---- Path A2: GEMM attention, softmax fused into U-GEMM epilogue ----
    unsigned short* U   = (unsigned short*)(ws + 0);          // 134.2 MB
    unsigned short* xb  = (unsigned short*)(ws + 0);          // overlay (dead after QKV)
    unsigned short* vb  = (unsigned short*)(ws + 8388608);    // overlay (dead after transp)
    unsigned short* att = (unsigned short*)(ws + 0);          // overlay (after PV)
    unsigned short* qb  = (unsigned short*)(ws + 134217728);
    unsigned short* kb  = (unsigned short*)(ws + 142606336);
    unsigned short* vtb = (unsigned short*)(ws + 150994944);
    unsigned short* wqT = (unsigned short*)(ws + 159383552);
    unsigned short* wkT = (unsigned short*)(ws + 159907840);
    unsigned short* wvT = (unsigned short*)(ws + 160432128);
    unsigned short* woT = (unsigned short*)(ws + 160956416);
    float* lpart = (float*)(ws + 161480704);                  // 4 MB [128][8192]
    float* linv  = (float*)(ws + 165675008);                  // 32 KB
    float* P0 = (float*)qb;        // 16 MB over qb+kb (dead after U-GEMM)
    float* P1 = (float*)d_out;     // overwritten by O-proj

    cvt_x_kernel<<<2048, 256, 0, stream>>>(x, xb, 8192 * 512 / 4);
    cvt_wT_kernel<<<dim3(16, 16, 4), 256, 0, stream>>>(Wq, Wk, Wv, Wo, wqT, wkT, wvT, woT);
    gemm_qkv_kernel<<<dim3(64, 4, 3), 256, 0, stream>>>(
        xb, wqT, wkT, wvT, bq, bk, bv, qb, kb, vb);
    transpose_v_kernel<<<dim3(16, 256), 256, 0, stream>>>(vb, vtb);
    gemm_u_kernel<<<dim3(64, 64), 256, 0, stream>>>(qb, kb, U, lpart);
    combine_l_kernel<<<32, 256, 0, stream>>>(lpart, linv);
    gemm_pv_kernel<<<dim3(4, 64, 2), 256, 0, stream>>>(U, vtb, P0, P1);
    addcvt_kernel<true><<<2048, 256, 0, stream>>>(P0, P1, linv, att, 8192 * 512 / 4);
    gemm_o_kernel<<<dim3(64, 4), 256, 0, stream>>>(att, woT, bo, (float*)d_out);
  } else if (ws_size >= 161480704ull) {
    // ---- Path A: two-pass GEMM attention (round-4) ----
    unsigned short* S   = (unsigned short*)(ws + 0);
    unsigned short* xb  = (unsigned short*)(ws + 0);
    unsigned short* vb  = (unsigned short*)(ws + 8388608);
    unsigned short* att = (unsigned short*)(ws + 0);
    unsigned short* qb  = (unsigned short*)(ws + 134217728);
    unsigned short* kb  = (unsigned short*)(ws + 142606336);
    unsigned short* vtb = (unsigned short*)(ws + 150994944);
    unsigned short* wqT = (unsigned short*)(ws + 159383552);
    unsigned short* wkT = (unsigned short*)(ws + 159907840);
    unsigned short* wvT = (unsigned short*)(ws + 160432128);
    unsigned short* woT = (unsigned short*)(ws + 160956416);
    float* P0 = (float*)qb;
    float* P1 = (float*)d_out;

    cvt_x_kernel<<<2048, 256, 0, stream>>>(x, xb, 8192 * 512 / 4);
    cvt_wT_kernel<<<dim3(16, 16, 4), 256, 0, stream>>>(Wq, Wk, Wv, Wo, wqT, wkT, wvT, woT);
    gemm_qkv_kernel<<<dim3(64, 4, 3), 256, 0, stream>>>(
        xb, wqT, wkT, wvT, bq, bk, bv, qb, kb, vb);
    transpose_v_kernel<<<dim3(16, 256), 256, 0, stream>>>(vb, vtb);
    gemm_s_kernel<<<dim3(64, 64), 256, 0, stream>>>(qb, kb, S);
    softmax_kernel<<<8192, 256, 0, stream>>>(S);
    gemm_pv_kernel<<<dim3(4, 64, 2), 256, 0, stream>>>(S, vtb, P0, P1);
    addcvt_kernel<false><<<2048, 256, 0, stream>>>(P0, P1, nullptr, att, 8192 * 512 / 4);
    gemm_o_kernel<<<dim3(64, 4), 256, 0, stream>>>(att, woT, bo, (float*)d_out);
  } else {
    // ---- Path B: flash fallback ----
    unsigned short* xb  = (unsigned short*)(ws + 0);
    unsigned short* qb  = (unsigned short*)(ws + 8388608);
    unsigned short* kb  = (unsigned short*)(ws + 16777216);
    unsigned short* vb  = (unsigned short*)(ws + 25165824);
    unsigned short* vtb = (unsigned short*)(ws + 33554432);
    unsigned short* att = (unsigned short*)(ws + 41943040);
    unsigned short* wqT = (unsigned short*)(ws + 50331648);
    unsigned short* wkT = (unsigned short*)(ws + 50855936);
    unsigned short* wvT = (unsigned short*)(ws + 51380224);
    unsigned short* woT = (unsigned short*)(ws + 51904512);
    float* ml   = (float*)(ws + 52428800);
    float* part = (float*)(ws + 52690944);
    int nsLog2 = (ws_size >= 119900000ull) ? 2 : 1;
    int NS = 1 << nsLog2;

    cvt_x_kernel<<<2048, 256, 0, stream>>>(x, xb, 8192 * 512 / 4);
    cvt_wT_kernel<<<dim3(16, 16, 4), 256, 0, stream>>>(Wq, Wk, Wv, Wo, wqT, wkT, wvT, woT);
    gemm_qkv_kernel<<<dim3(64, 4, 3), 256, 0, stream>>>(
        xb, wqT, wkT, wvT, bq, bk, bv, qb, kb, vb);
    transpose_v_kernel<<<dim3(16, 256), 256, 0, stream>>>(vb, vtb);
    flash_kernel<<<128 * NS, 256, 0, stream>>>(qb, kb, vtb, part, ml, nsLog2);
    if (NS == 4) combine_kernel<4><<<1024, 256, 0, stream>>>(part, ml, att);
    else         combine_kernel<2><<<1024, 256, 0, stream>>>(part, ml, att);
    gemm_o_kernel<<<dim3(64, 4), 256, 0, stream>>>(att, woT, bo, (float*)d_out);
  }
}

// Round 6
// 263.239 us; speedup vs baseline: 2.5398x; 1.0023x over previous
//
#include <hip/hip_runtime.h>

// ---------- common ----------
typedef short sh8 __attribute__((ext_vector_type(8)));
typedef float f32x4 __attribute__((ext_vector_type(4)));

#define DEV __device__ __forceinline__

DEV f32x4 mfma16(sh8 a, sh8 b, f32x4 c) {
  return __builtin_amdgcn_mfma_f32_16x16x32_bf16(a, b, c, 0, 0, 0);
}

DEV unsigned short f2bf(float f) {
  unsigned u = __float_as_uint(f);
  u = u + 0x7FFFu + ((u >> 16) & 1u);   // RNE
  return (unsigned short)(u >> 16);
}

DEV unsigned cvtpk(float lo, float hi) {
  unsigned r;
  asm("v_cvt_pk_bf16_f32 %0, %1, %2" : "=v"(r) : "v"(lo), "v"(hi));
  return r;
}

DEV void gll16(const void* g, void* l) {
  __builtin_amdgcn_global_load_lds(
      (const __attribute__((address_space(1))) unsigned int*)g,
      (__attribute__((address_space(3))) unsigned int*)l, 16, 0, 0);
}

// ---------- kernel: x fp32 -> bf16 ----------
__global__ void cvt_x_kernel(const float* __restrict__ x, unsigned short* __restrict__ xb, int n4) {
  int i = blockIdx.x * blockDim.x + threadIdx.x;
  int stride = gridDim.x * blockDim.x;
  for (; i < n4; i += stride) {
    float4 v = ((const float4*)x)[i];
    ushort4 o;
    o.x = f2bf(v.x); o.y = f2bf(v.y); o.z = f2bf(v.z); o.w = f2bf(v.w);
    ((ushort4*)xb)[i] = o;
  }
}

// ---------- kernel: weight transpose + cvt ----------
__global__ void cvt_wT_kernel(const float* __restrict__ W0, const float* __restrict__ W1,
                              const float* __restrict__ W2, const float* __restrict__ W3,
                              unsigned short* __restrict__ T0, unsigned short* __restrict__ T1,
                              unsigned short* __restrict__ T2, unsigned short* __restrict__ T3) {
  const float* W; unsigned short* T;
  switch (blockIdx.z) {
    case 0: W = W0; T = T0; break;
    case 1: W = W1; T = T1; break;
    case 2: W = W2; T = T2; break;
    default: W = W3; T = T3; break;
  }
  __shared__ float tile[32][33];
  int tx = threadIdx.x & 31, ty = threadIdx.x >> 5;
  int r0 = blockIdx.y * 32, c0 = blockIdx.x * 32;
#pragma unroll
  for (int i = 0; i < 4; i++) tile[ty + i * 8][tx] = W[(r0 + ty + i * 8) * 512 + c0 + tx];
  __syncthreads();
#pragma unroll
  for (int i = 0; i < 4; i++) T[(c0 + ty + i * 8) * 512 + r0 + tx] = f2bf(tile[tx][ty + i * 8]);
}

// ---------- GEMM core (BK=64, double-buffered 2-phase pipeline) ----------
// 128x128 tile, 4 waves (2x2). Per K-step: issue next tile's 8x gll16
// (XOR-swizzled src, linear dest) BEFORE computing current tile from the
// other LDS buffer; single vmcnt(0)+barrier at step end (T3-min recipe).
// MODE: 0 = fp32 direct store (+bias), 1 = bf16 via LDS coalesced store
// (+bias), 2 = exp2(acc*c) bf16 coalesced + per-block row-sums to lpart.
template <int MODE>
DEV void gemm_core(const unsigned short* __restrict__ A, int lda,
                   const unsigned short* __restrict__ Bt, int ldb,
                   const float* __restrict__ bias, void* __restrict__ Cv, int ldc,
                   int kSteps, int koff, int brow, int bcol,
                   float* __restrict__ lpart, unsigned short* smem) {
  const int tid = threadIdx.x, lane = tid & 63, w = tid >> 6;
  const int g = lane >> 4, r = lane & 15;
  const int wr = w >> 1, wc = w & 1;
  const int rA = w * 8 + (lane >> 3);           // staging row (cc=0)
  const int sgl = lane & 7;                     // dest granule (linear)
  const int scol = ((sgl ^ (lane >> 3)) * 8);   // pre-swizzled src col
  const unsigned short* aP = A + (size_t)(brow + rA) * lda + koff + scol;
  const unsigned short* bP = Bt + (size_t)(bcol + rA) * ldb + koff + scol;
  const int lOff = rA * 64 + sgl * 8;
  f32x4 acc[4][4] = {};
  const int fr = r & 7;

  auto STAGE = [&](int buf, int ks) {
    unsigned short* lA = smem + buf * 16384 + lOff;
    unsigned short* lB = smem + buf * 16384 + 8192 + lOff;
    const size_t ko = (size_t)ks * 64;
#pragma unroll
    for (int cc = 0; cc < 4; cc++) gll16(aP + (size_t)cc * 32 * lda + ko, lA + cc * 32 * 64);
#pragma unroll
    for (int cc = 0; cc < 4; cc++) gll16(bP + (size_t)cc * 32 * ldb + ko, lB + cc * 32 * 64);
  };
  auto COMPUTE = [&](int buf) {
    const unsigned short* As = smem + buf * 16384;
    const unsigned short* Bs = As + 8192;
#pragma unroll
    for (int kk = 0; kk < 2; kk++) {
      sh8 af[4], bfr[4];
#pragma unroll
      for (int m = 0; m < 4; m++)
        af[m] = *(const sh8*)&As[(wr * 64 + m * 16 + r) * 64 + (((kk * 4 + g) ^ fr) * 8)];
#pragma unroll
      for (int n = 0; n < 4; n++)
        bfr[n] = *(const sh8*)&Bs[(wc * 64 + n * 16 + r) * 64 + (((kk * 4 + g) ^ fr) * 8)];
#pragma unroll
      for (int m = 0; m < 4; m++)
#pragma unroll
        for (int n = 0; n < 4; n++) acc[m][n] = mfma16(af[m], bfr[n], acc[m][n]);
    }
  };

  STAGE(0, 0);
  asm volatile("s_waitcnt vmcnt(0)" ::: "memory");
  __syncthreads();
  int cur = 0;
  for (int ks = 0; ks + 1 < kSteps; ks++) {
    STAGE(cur ^ 1, ks + 1);       // prefetch next tile (in flight under compute)
    COMPUTE(cur);
    asm volatile("s_waitcnt vmcnt(0)" ::: "memory");
    __syncthreads();
    cur ^= 1;
  }
  COMPUTE(cur);

  const float K2c = 0.04419417382415922f * 1.4426950408889634f;  // 1/sqrt(512)*log2e
  if (MODE == 0) {
#pragma unroll
    for (int n = 0; n < 4; n++) {
      int col = bcol + wc * 64 + n * 16 + r;
      float bv = bias ? bias[col] : 0.f;
#pragma unroll
      for (int m = 0; m < 4; m++) {
        int row = brow + wr * 64 + m * 16 + g * 4;
#pragma unroll
        for (int i = 0; i < 4; i++)
          ((float*)Cv)[(size_t)(row + i) * ldc + col] = acc[m][n][i] + bv;
      }
    }
  } else {
    __syncthreads();  // all waves done reading staging LDS before reuse
#pragma unroll
    for (int m = 0; m < 4; m++) {
      float rs0 = 0.f, rs1 = 0.f, rs2 = 0.f, rs3 = 0.f;
#pragma unroll
      for (int n = 0; n < 4; n++) {
        int coll = wc * 64 + n * 16 + r;
        float bv = (MODE == 1 && bias) ? bias[bcol + coll] : 0.f;
        float v0 = acc[m][n][0] + bv, v1 = acc[m][n][1] + bv;
        float v2 = acc[m][n][2] + bv, v3 = acc[m][n][3] + bv;
        if (MODE == 2) {
          v0 = __builtin_amdgcn_exp2f(v0 * K2c); rs0 += v0;
          v1 = __builtin_amdgcn_exp2f(v1 * K2c); rs1 += v1;
          v2 = __builtin_amdgcn_exp2f(v2 * K2c); rs2 += v2;
          v3 = __builtin_amdgcn_exp2f(v3 * K2c); rs3 += v3;
        }
        int rb = (wr * 64 + m * 16 + g * 4) * 132 + coll;
        smem[rb] = f2bf(v0);
        smem[rb + 132] = f2bf(v1);
        smem[rb + 264] = f2bf(v2);
        smem[rb + 396] = f2bf(v3);
      }
      if (MODE == 2) {
        float rs[4] = {rs0, rs1, rs2, rs3};
#pragma unroll
        for (int i = 0; i < 4; i++) {
          float t = rs[i];
          t += __shfl_xor(t, 1); t += __shfl_xor(t, 2);
          t += __shfl_xor(t, 4); t += __shfl_xor(t, 8);
          if (r == 0)
            lpart[(size_t)((bcol >> 7) * 2 + wc) * 8192 + brow + wr * 64 + m * 16 + g * 4 + i] = t;
        }
      }
    }
    __syncthreads();
    unsigned short* C = (unsigned short*)Cv;
#pragma unroll
    for (int j = 0; j < 8; j++) {
      int row = w * 32 + j * 4 + (lane >> 4);
      int colb = (lane & 15) * 8;
      uint4 v = *(const uint4*)&smem[row * 132 + colb];
      *(uint4*)&C[(size_t)(brow + row) * ldc + bcol + colb] = v;
    }
  }
}

// ---------- GEMM wrappers (smem: 2 x 32KB staging dbuf, reused by epilogue) ----------
__global__ __launch_bounds__(256, 2) void gemm_qkv_kernel(
    const unsigned short* __restrict__ A,
    const unsigned short* __restrict__ B0, const unsigned short* __restrict__ B1,
    const unsigned short* __restrict__ B2,
    const float* __restrict__ c0, const float* __restrict__ c1, const float* __restrict__ c2,
    unsigned short* __restrict__ C0, unsigned short* __restrict__ C1,
    unsigned short* __restrict__ C2) {
  __shared__ __align__(16) unsigned short smem[32768];
  const unsigned short* Bt; const float* bias; unsigned short* C;
  switch (blockIdx.z) {
    case 0: Bt = B0; bias = c0; C = C0; break;
    case 1: Bt = B1; bias = c1; C = C1; break;
    default: Bt = B2; bias = c2; C = C2; break;
  }
  gemm_core<1>(A, 512, Bt, 512, bias, C, 512, 8, 0,
               blockIdx.x * 128, blockIdx.y * 128, nullptr, smem);
}

__global__ __launch_bounds__(256, 2) void gemm_u_kernel(
    const unsigned short* __restrict__ Q, const unsigned short* __restrict__ Kb,
    unsigned short* __restrict__ U, float* __restrict__ lpart) {
  __shared__ __align__(16) unsigned short smem[32768];
  gemm_core<2>(Q, 512, Kb, 512, nullptr, U, 8192, 8, 0,
               blockIdx.x * 128, blockIdx.y * 128, lpart, smem);
}

__global__ __launch_bounds__(256, 2) void gemm_pv_kernel(
    const unsigned short* __restrict__ U, const unsigned short* __restrict__ VT,
    float* __restrict__ P0, float* __restrict__ P1) {
  __shared__ __align__(16) unsigned short smem[32768];
  float* P = blockIdx.z ? P1 : P0;
  gemm_core<0>(U, 8192, VT, 8192, nullptr, P, 512, 64, blockIdx.z * 4096,
               blockIdx.y * 128, blockIdx.x * 128, nullptr, smem);
}

__global__ __launch_bounds__(256, 2) void gemm_o_kernel(
    const unsigned short* __restrict__ att, const unsigned short* __restrict__ woT,
    const float* __restrict__ bo, float* __restrict__ out) {
  __shared__ __align__(16) unsigned short smem[32768];
  gemm_core<0>(att, 512, woT, 512, bo, out, 512, 8, 0,
               blockIdx.x * 128, blockIdx.y * 128, nullptr, smem);
}

// ---------- kernel: v [8192][512] -> vT [512][8192] (bf16) ----------
__global__ void transpose_v_kernel(const unsigned short* __restrict__ in, unsigned short* __restrict__ out) {
  __shared__ unsigned short tile[32][33];
  int tx = threadIdx.x & 31, ty = threadIdx.x >> 5;
  int r0 = blockIdx.y * 32, c0 = blockIdx.x * 32;
#pragma unroll
  for (int i = 0; i < 4; i++) tile[ty + i * 8][tx] = in[(size_t)(r0 + ty + i * 8) * 512 + c0 + tx];
  __syncthreads();
#pragma unroll
  for (int i = 0; i < 4; i++) out[(size_t)(c0 + ty + i * 8) * 8192 + r0 + tx] = tile[tx][ty + i * 8];
}

// ---------- combine row-sum partials -> 1/l ----------
__global__ void combine_l_kernel(const float* __restrict__ lpart, float* __restrict__ linv) {
  int row = blockIdx.x * 256 + threadIdx.x;
  float s = 0.f;
#pragma unroll 8
  for (int j = 0; j < 128; j++) s += lpart[(size_t)j * 8192 + row];
  linv[row] = 1.0f / s;
}

// ---------- add two fp32 partials (optionally * linv[row]) -> bf16 ----------
template <bool NORM>
__global__ void addcvt_kernel(const float* __restrict__ a, const float* __restrict__ b,
                              const float* __restrict__ linv,
                              unsigned short* __restrict__ o, int n4) {
  int i = blockIdx.x * blockDim.x + threadIdx.x;
  int stride = gridDim.x * blockDim.x;
  for (; i < n4; i += stride) {
    float inv = NORM ? linv[i >> 7] : 1.0f;
    float4 va = ((const float4*)a)[i];
    float4 vb = ((const float4*)b)[i];
    ushort4 ov;
    ov.x = f2bf((va.x + vb.x) * inv); ov.y = f2bf((va.y + vb.y) * inv);
    ov.z = f2bf((va.z + vb.z) * inv); ov.w = f2bf((va.w + vb.w) * inv);
    ((ushort4*)o)[i] = ov;
  }
}

// ---------- deep fallback: flash attention ----------
__global__ __launch_bounds__(256, 2) void flash_kernel(
    const unsigned short* __restrict__ Q, const unsigned short* __restrict__ Kb,
    const unsigned short* __restrict__ VT, float* __restrict__ Pout,
    float* __restrict__ ML, int nsLog2) {
  __shared__ __align__(16) unsigned short k_lds[2][32][512];
  __shared__ __align__(16) unsigned short p_lds[4][16][32];
  const int tid = threadIdx.x;
  const int lane = tid & 63, w = tid >> 6;
  const int g = lane >> 4, r = lane & 15;
  const int ns = 1 << nsLog2;
  const int split = blockIdx.x & (ns - 1);
  const int qblk = blockIdx.x >> nsLog2;
  const int qbase = qblk * 64 + w * 16;
  const int kvlen = 8192 >> nsLog2;
  const int kv0 = split * kvlen;
  const int nsteps = kvlen >> 5;
  sh8 qa[16];
#pragma unroll
  for (int dc = 0; dc < 16; dc++)
    qa[dc] = *(const sh8*)&Q[(qbase + r) * 512 + dc * 32 + g * 8];
  f32x4 acc[32] = {};
  float mrow = -1e30f, lrow = 0.f;
  const float K2r = 0.04419417382415922f * 1.4426950408889634f;
#pragma unroll
  for (int ii = 0; ii < 8; ii++) {
    int row = w * 8 + ii;
    gll16(Kb + (size_t)(kv0 + row) * 512 + (size_t)((lane ^ ii) * 8), &k_lds[0][row][0]);
  }
  int cur = 0;
  const int swz = (r & 7) * 8;
  for (int s = 0; s < nsteps; s++) {
    const int kvrow0 = kv0 + s * 32;
    asm volatile("s_waitcnt vmcnt(0)" ::: "memory");
    __syncthreads();
    if (s + 1 < nsteps) {
#pragma unroll
      for (int ii = 0; ii < 8; ii++) {
        int row = w * 8 + ii;
        gll16(Kb + (size_t)(kvrow0 + 32 + row) * 512 + (size_t)((lane ^ ii) * 8),
              &k_lds[cur ^ 1][row][0]);
      }
    }
    f32x4 sA0 = {0.f, 0.f, 0.f, 0.f};
    f32x4 sA1 = {0.f, 0.f, 0.f, 0.f};
#pragma unroll
    for (int dc = 0; dc < 16; dc++) {
      int co = (dc * 32 + g * 8) ^ swz;
      sh8 kf0 = *(const sh8*)&k_lds[cur][r][co];
      sh8 kf1 = *(const sh8*)&k_lds[cur][16 + r][co];
      sA0 = mfma16(kf0, qa[dc], sA0);
      sA1 = mfma16(kf1, qa[dc], sA1);
    }
    float rmax = fmaxf(fmaxf(fmaxf(sA0[0], sA0[1]), fmaxf(sA0[2], sA0[3])),
                       fmaxf(fmaxf(sA1[0], sA1[1]), fmaxf(sA1[2], sA1[3])));
    rmax = fmaxf(rmax, __shfl_xor(rmax, 16));
    rmax = fmaxf(rmax, __shfl_xor(rmax, 32));
    float tmax = rmax * K2r;
    if (__any(tmax > mrow + 4.0f)) {
      float mn = fmaxf(mrow, tmax);
      float corr = __builtin_amdgcn_exp2f(mrow - mn);
      mrow = mn;
      lrow *= corr;
      f32x4 cv;
      cv[0] = __shfl(corr, 4 * g + 0);
      cv[1] = __shfl(corr, 4 * g + 1);
      cv[2] = __shfl(corr, 4 * g + 2);
      cv[3] = __shfl(corr, 4 * g + 3);
#pragma unroll
      for (int dt = 0; dt < 32; dt++) acc[dt] *= cv;
    }
    float p0 = __builtin_amdgcn_exp2f(fmaf(sA0[0], K2r, -mrow));
    float p1 = __builtin_amdgcn_exp2f(fmaf(sA0[1], K2r, -mrow));
    float p2 = __builtin_amdgcn_exp2f(fmaf(sA0[2], K2r, -mrow));
    float p3 = __builtin_amdgcn_exp2f(fmaf(sA0[3], K2r, -mrow));
    float p4 = __builtin_amdgcn_exp2f(fmaf(sA1[0], K2r, -mrow));
    float p5 = __builtin_amdgcn_exp2f(fmaf(sA1[1], K2r, -mrow));
    float p6 = __builtin_amdgcn_exp2f(fmaf(sA1[2], K2r, -mrow));
    float p7 = __builtin_amdgcn_exp2f(fmaf(sA1[3], K2r, -mrow));
    float ps = ((p0 + p1) + (p2 + p3)) + ((p4 + p5) + (p6 + p7));
    ps += __shfl_xor(ps, 16);
    ps += __shfl_xor(ps, 32);
    lrow += ps;
    uint2 w0, w1;
    w0.x = cvtpk(p0, p1); w0.y = cvtpk(p2, p3);
    w1.x = cvtpk(p4, p5); w1.y = cvtpk(p6, p7);
    *(uint2*)&p_lds[w][r][4 * g] = w0;
    *(uint2*)&p_lds[w][r][16 + 4 * g] = w1;
    sh8 pf = *(const sh8*)&p_lds[w][r][8 * g];
#pragma unroll
    for (int dt = 0; dt < 32; dt++) {
      sh8 vf = *(const sh8*)&VT[(dt * 16 + r) * 8192 + kvrow0 + g * 8];
      acc[dt] = mfma16(pf, vf, acc[dt]);
    }
    cur ^= 1;
  }
  float* P = Pout + (size_t)split * 4194304;
#pragma unroll
  for (int dt = 0; dt < 32; dt++)
#pragma unroll
    for (int i = 0; i < 4; i++)
      P[(qbase + 4 * g + i) * 512 + dt * 16 + r] = acc[dt][i];
  if (g == 0) {
    ML[(split * 2 + 0) * 8192 + qbase + r] = mrow;
    ML[(split * 2 + 1) * 8192 + qbase + r] = lrow;
  }
}

template <int NS>
__global__ void combine_kernel(const float* __restrict__ Pp, const float* __restrict__ ML,
                               unsigned short* __restrict__ att) {
  int idx = blockIdx.x * blockDim.x + threadIdx.x;
  int stride = gridDim.x * blockDim.x;
  for (int i4 = idx; i4 < 8192 * 512 / 4; i4 += stride) {
    int row = i4 >> 7;
    float m[NS], l[NS], e[NS];
    float mm = -1e30f;
#pragma unroll
    for (int s2 = 0; s2 < NS; s2++) {
      m[s2] = ML[(s2 * 2 + 0) * 8192 + row];
      l[s2] = ML[(s2 * 2 + 1) * 8192 + row];
      mm = fmaxf(mm, m[s2]);
    }
    float den = 0.f;
#pragma unroll
    for (int s2 = 0; s2 < NS; s2++) {
      e[s2] = __builtin_amdgcn_exp2f(m[s2] - mm);
      den += l[s2] * e[s2];
    }
    float inv = 1.0f / den;
    float ox = 0.f, oy = 0.f, oz = 0.f, ow = 0.f;
#pragma unroll
    for (int s2 = 0; s2 < NS; s2++) {
      float4 a = ((const float4*)(Pp + (size_t)s2 * 4194304))[i4];
      ox += a.x * e[s2]; oy += a.y * e[s2]; oz += a.z * e[s2]; ow += a.w * e[s2];
    }
    ushort4 ov;
    ov.x = f2bf(ox * inv); ov.y = f2bf(oy * inv);
    ov.z = f2bf(oz * inv); ov.w = f2bf(ow * inv);
    ((ushort4*)att)[i4] = ov;
  }
}

// ---------- launch ----------
extern "C" void kernel_launch(void* const* d_in, const int* in_sizes, int n_in,
                              void* d_out, int out_size, void* d_ws, size_t ws_size,
                              hipStream_t stream) {
  const float* x  = (const float*)d_in[0];
  const float* Wq = (const float*)d_in[1];
  const float* bq = (const float*)d_in[2];
  const float* Wk = (const float*)d_in[3];
  const float* bk = (const float*)d_in[4];
  const float* Wv = (const float*)d_in[5];
  const float* bv = (const float*)d_in[6];
  const float* Wo = (const float*)d_in[7];
  const float* bo = (const float*)d_in[8];
  char* ws = (char*)d_ws;

  if (ws_size >= 165707776ull) {
    // ---- Path A2: GEMM attention, softmax fused into U-GEMM epilogue ----
    unsigned short* U   = (unsigned short*)(ws + 0);          // 134.2 MB
    unsigned short* xb  = (unsigned short*)(ws + 0);          // overlay (dead after QKV)
    unsigned short* vb  = (unsigned short*)(ws + 8388608);    // overlay (dead after transp)
    unsigned short* att = (unsigned short*)(ws + 0);          // overlay (after PV)
    unsigned short* qb  = (unsigned short*)(ws + 134217728);
    unsigned short* kb  = (unsigned short*)(ws + 142606336);
    unsigned short* vtb = (unsigned short*)(ws + 150994944);
    unsigned short* wqT = (unsigned short*)(ws + 159383552);
    unsigned short* wkT = (unsigned short*)(ws + 159907840);
    unsigned short* wvT = (unsigned short*)(ws + 160432128);
    unsigned short* woT = (unsigned short*)(ws + 160956416);
    float* lpart = (float*)(ws + 161480704);                  // 4 MB [128][8192]
    float* linv  = (float*)(ws + 165675008);                  // 32 KB
    float* P0 = (float*)qb;        // 16 MB over qb+kb (dead after U-GEMM)
    float* P1 = (float*)d_out;     // overwritten by O-proj

    cvt_x_kernel<<<2048, 256, 0, stream>>>(x, xb, 8192 * 512 / 4);
    cvt_wT_kernel<<<dim3(16, 16, 4), 256, 0, stream>>>(Wq, Wk, Wv, Wo, wqT, wkT, wvT, woT);
    gemm_qkv_kernel<<<dim3(64, 4, 3), 256, 0, stream>>>(
        xb, wqT, wkT, wvT, bq, bk, bv, qb, kb, vb);
    transpose_v_kernel<<<dim3(16, 256), 256, 0, stream>>>(vb, vtb);
    gemm_u_kernel<<<dim3(64, 64), 256, 0, stream>>>(qb, kb, U, lpart);
    combine_l_kernel<<<32, 256, 0, stream>>>(lpart, linv);
    gemm_pv_kernel<<<dim3(4, 64, 2), 256, 0, stream>>>(U, vtb, P0, P1);
    addcvt_kernel<true><<<2048, 256, 0, stream>>>(P0, P1, linv, att, 8192 * 512 / 4);
    gemm_o_kernel<<<dim3(64, 4), 256, 0, stream>>>(att, woT, bo, (float*)d_out);
  } else {
    // ---- Path B: flash fallback ----
    unsigned short* xb  = (unsigned short*)(ws + 0);
    unsigned short* qb  = (unsigned short*)(ws + 8388608);
    unsigned short* kb  = (unsigned short*)(ws + 16777216);
    unsigned short* vb  = (unsigned short*)(ws + 25165824);
    unsigned short* vtb = (unsigned short*)(ws + 33554432);
    unsigned short* att = (unsigned short*)(ws + 41943040);
    unsigned short* wqT = (unsigned short*)(ws + 50331648);
    unsigned short* wkT = (unsigned short*)(ws + 50855936);
    unsigned short* wvT = (unsigned short*)(ws + 51380224);
    unsigned short* woT = (unsigned short*)(ws + 51904512);
    float* ml   = (float*)(ws + 52428800);
    float* part = (float*)(ws + 52690944);
    int nsLog2 = (ws_size >= 119900000ull) ? 2 : 1;
    int NS = 1 << nsLog2;

    cvt_x_kernel<<<2048, 256, 0, stream>>>(x, xb, 8192 * 512 / 4);
    cvt_wT_kernel<<<dim3(16, 16, 4), 256, 0, stream>>>(Wq, Wk, Wv, Wo, wqT, wkT, wvT, woT);
    gemm_qkv_kernel<<<dim3(64, 4, 3), 256, 0, stream>>>(
        xb, wqT, wkT, wvT, bq, bk, bv, qb, kb, vb);
    transpose_v_kernel<<<dim3(16, 256), 256, 0, stream>>>(vb, vtb);
    flash_kernel<<<128 * NS, 256, 0, stream>>>(qb, kb, vtb, part, ml, nsLog2);
    if (NS == 4) combine_kernel<4><<<1024, 256, 0, stream>>>(part, ml, att);
    else         combine_kernel<2><<<1024, 256, 0, stream>>>(part, ml, att);
    gemm_o_kernel<<<dim3(64, 4), 256, 0, stream>>>(att, woT, bo, (float*)d_out);
  }
}

// Round 7
// 259.640 us; speedup vs baseline: 2.5750x; 1.0139x over previous
//
#include <hip/hip_runtime.h>

// ---------- common ----------
typedef short sh8 __attribute__((ext_vector_type(8)));
typedef float f32x4 __attribute__((ext_vector_type(4)));

#define DEV __device__ __forceinline__

DEV f32x4 mfma16(sh8 a, sh8 b, f32x4 c) {
  return __builtin_amdgcn_mfma_f32_16x16x32_bf16(a, b, c, 0, 0, 0);
}

DEV unsigned short f2bf(float f) {
  unsigned u = __float_as_uint(f);
  u = u + 0x7FFFu + ((u >> 16) & 1u);   // RNE
  return (unsigned short)(u >> 16);
}

DEV unsigned cvtpk(float lo, float hi) {
  unsigned r;
  asm("v_cvt_pk_bf16_f32 %0, %1, %2" : "=v"(r) : "v"(lo), "v"(hi));
  return r;
}

DEV void gll16(const void* g, void* l) {
  __builtin_amdgcn_global_load_lds(
      (const __attribute__((address_space(1))) unsigned int*)g,
      (__attribute__((address_space(3))) unsigned int*)l, 16, 0, 0);
}

// ---------- kernel: x fp32 -> bf16 ----------
__global__ void cvt_x_kernel(const float* __restrict__ x, unsigned short* __restrict__ xb, int n4) {
  int i = blockIdx.x * blockDim.x + threadIdx.x;
  int stride = gridDim.x * blockDim.x;
  for (; i < n4; i += stride) {
    float4 v = ((const float4*)x)[i];
    ushort4 o;
    o.x = f2bf(v.x); o.y = f2bf(v.y); o.z = f2bf(v.z); o.w = f2bf(v.w);
    ((ushort4*)xb)[i] = o;
  }
}

// ---------- kernel: weight transpose + cvt ----------
__global__ void cvt_wT_kernel(const float* __restrict__ W0, const float* __restrict__ W1,
                              const float* __restrict__ W2, const float* __restrict__ W3,
                              unsigned short* __restrict__ T0, unsigned short* __restrict__ T1,
                              unsigned short* __restrict__ T2, unsigned short* __restrict__ T3) {
  const float* W; unsigned short* T;
  switch (blockIdx.z) {
    case 0: W = W0; T = T0; break;
    case 1: W = W1; T = T1; break;
    case 2: W = W2; T = T2; break;
    default: W = W3; T = T3; break;
  }
  __shared__ float tile[32][33];
  int tx = threadIdx.x & 31, ty = threadIdx.x >> 5;
  int r0 = blockIdx.y * 32, c0 = blockIdx.x * 32;
#pragma unroll
  for (int i = 0; i < 4; i++) tile[ty + i * 8][tx] = W[(r0 + ty + i * 8) * 512 + c0 + tx];
  __syncthreads();
#pragma unroll
  for (int i = 0; i < 4; i++) T[(c0 + ty + i * 8) * 512 + r0 + tx] = f2bf(tile[tx][ty + i * 8]);
}

// ---------- GEMM core (BK=64, dbuf + COUNTED vmcnt pipeline, T4) ----------
// 128x128 tile, 4 waves (2x2). Per K-step: issue next tile's 8x gll16, then
// s_waitcnt vmcnt(8) (waits ONLY for current tile; next tile's 8 loads stay
// in flight across the barriers), raw s_barrier, 32 MFMA, raw s_barrier.
// Final tile drains vmcnt(0). MODE: 0 = fp32 direct store (+bias),
// 1 = bf16 via LDS coalesced store (+bias), 2 = exp2(acc*c) bf16 coalesced
// + per-block row-sums to lpart.
template <int MODE>
DEV void gemm_core(const unsigned short* __restrict__ A, int lda,
                   const unsigned short* __restrict__ Bt, int ldb,
                   const float* __restrict__ bias, void* __restrict__ Cv, int ldc,
                   int kSteps, int koff, int brow, int bcol,
                   float* __restrict__ lpart, unsigned short* smem) {
  const int tid = threadIdx.x, lane = tid & 63, w = tid >> 6;
  const int g = lane >> 4, r = lane & 15;
  const int wr = w >> 1, wc = w & 1;
  const int rA = w * 8 + (lane >> 3);           // staging row (cc=0)
  const int sgl = lane & 7;                     // dest granule (linear)
  const int scol = ((sgl ^ (lane >> 3)) * 8);   // pre-swizzled src col
  const unsigned short* aP = A + (size_t)(brow + rA) * lda + koff + scol;
  const unsigned short* bP = Bt + (size_t)(bcol + rA) * ldb + koff + scol;
  const int lOff = rA * 64 + sgl * 8;
  f32x4 acc[4][4] = {};
  const int fr = r & 15 & 7;

  auto STAGE = [&](int buf, int ks) {
    unsigned short* lA = smem + buf * 16384 + lOff;
    unsigned short* lB = smem + buf * 16384 + 8192 + lOff;
    const size_t ko = (size_t)ks * 64;
#pragma unroll
    for (int cc = 0; cc < 4; cc++) gll16(aP + (size_t)cc * 32 * lda + ko, lA + cc * 32 * 64);
#pragma unroll
    for (int cc = 0; cc < 4; cc++) gll16(bP + (size_t)cc * 32 * ldb + ko, lB + cc * 32 * 64);
  };
  auto COMPUTE = [&](int buf) {
    const unsigned short* As = smem + buf * 16384;
    const unsigned short* Bs = As + 8192;
#pragma unroll
    for (int kk = 0; kk < 2; kk++) {
      sh8 af[4], bfr[4];
#pragma unroll
      for (int m = 0; m < 4; m++)
        af[m] = *(const sh8*)&As[(wr * 64 + m * 16 + r) * 64 + (((kk * 4 + g) ^ fr) * 8)];
#pragma unroll
      for (int n = 0; n < 4; n++)
        bfr[n] = *(const sh8*)&Bs[(wc * 64 + n * 16 + r) * 64 + (((kk * 4 + g) ^ fr) * 8)];
#pragma unroll
      for (int m = 0; m < 4; m++)
#pragma unroll
        for (int n = 0; n < 4; n++) acc[m][n] = mfma16(af[m], bfr[n], acc[m][n]);
    }
  };

  STAGE(0, 0);
  int cur = 0;
  for (int ks = 0; ks + 1 < kSteps; ks++) {
    STAGE(cur ^ 1, ks + 1);                                  // 8 more in flight
    asm volatile("s_waitcnt vmcnt(8)" ::: "memory");         // current tile done
    asm volatile("s_barrier" ::: "memory");
    COMPUTE(cur);
    asm volatile("s_barrier" ::: "memory");                  // buffer free for restage
    cur ^= 1;
  }
  asm volatile("s_waitcnt vmcnt(0)" ::: "memory");
  asm volatile("s_barrier" ::: "memory");
  COMPUTE(cur);

  const float K2c = 0.04419417382415922f * 1.4426950408889634f;  // 1/sqrt(512)*log2e
  if (MODE == 0) {
#pragma unroll
    for (int n = 0; n < 4; n++) {
      int col = bcol + wc * 64 + n * 16 + r;
      float bv = bias ? bias[col] : 0.f;
#pragma unroll
      for (int m = 0; m < 4; m++) {
        int row = brow + wr * 64 + m * 16 + g * 4;
#pragma unroll
        for (int i = 0; i < 4; i++)
          ((float*)Cv)[(size_t)(row + i) * ldc + col] = acc[m][n][i] + bv;
      }
    }
  } else {
    __syncthreads();  // all waves done reading staging LDS before reuse
#pragma unroll
    for (int m = 0; m < 4; m++) {
      float rs0 = 0.f, rs1 = 0.f, rs2 = 0.f, rs3 = 0.f;
#pragma unroll
      for (int n = 0; n < 4; n++) {
        int coll = wc * 64 + n * 16 + r;
        float bv = (MODE == 1 && bias) ? bias[bcol + coll] : 0.f;
        float v0 = acc[m][n][0] + bv, v1 = acc[m][n][1] + bv;
        float v2 = acc[m][n][2] + bv, v3 = acc[m][n][3] + bv;
        if (MODE == 2) {
          v0 = __builtin_amdgcn_exp2f(v0 * K2c); rs0 += v0;
          v1 = __builtin_amdgcn_exp2f(v1 * K2c); rs1 += v1;
          v2 = __builtin_amdgcn_exp2f(v2 * K2c); rs2 += v2;
          v3 = __builtin_amdgcn_exp2f(v3 * K2c); rs3 += v3;
        }
        int rb = (wr * 64 + m * 16 + g * 4) * 132 + coll;
        smem[rb] = f2bf(v0);
        smem[rb + 132] = f2bf(v1);
        smem[rb + 264] = f2bf(v2);
        smem[rb + 396] = f2bf(v3);
      }
      if (MODE == 2) {
        float rs[4] = {rs0, rs1, rs2, rs3};
#pragma unroll
        for (int i = 0; i < 4; i++) {
          float t = rs[i];
          t += __shfl_xor(t, 1); t += __shfl_xor(t, 2);
          t += __shfl_xor(t, 4); t += __shfl_xor(t, 8);
          if (r == 0)
            lpart[(size_t)((bcol >> 7) * 2 + wc) * 8192 + brow + wr * 64 + m * 16 + g * 4 + i] = t;
        }
      }
    }
    __syncthreads();
    unsigned short* C = (unsigned short*)Cv;
#pragma unroll
    for (int j = 0; j < 8; j++) {
      int row = w * 32 + j * 4 + (lane >> 4);
      int colb = (lane & 15) * 8;
      uint4 v = *(const uint4*)&smem[row * 132 + colb];
      *(uint4*)&C[(size_t)(brow + row) * ldc + bcol + colb] = v;
    }
  }
}

// ---------- GEMM wrappers (smem: 2 x 32KB staging dbuf, reused by epilogue) ----------
__global__ __launch_bounds__(256, 2) void gemm_qkv_kernel(
    const unsigned short* __restrict__ A,
    const unsigned short* __restrict__ B0, const unsigned short* __restrict__ B1,
    const unsigned short* __restrict__ B2,
    const float* __restrict__ c0, const float* __restrict__ c1, const float* __restrict__ c2,
    unsigned short* __restrict__ C0, unsigned short* __restrict__ C1,
    unsigned short* __restrict__ C2) {
  __shared__ __align__(16) unsigned short smem[32768];
  const unsigned short* Bt; const float* bias; unsigned short* C;
  switch (blockIdx.z) {
    case 0: Bt = B0; bias = c0; C = C0; break;
    case 1: Bt = B1; bias = c1; C = C1; break;
    default: Bt = B2; bias = c2; C = C2; break;
  }
  gemm_core<1>(A, 512, Bt, 512, bias, C, 512, 8, 0,
               blockIdx.x * 128, blockIdx.y * 128, nullptr, smem);
}

__global__ __launch_bounds__(256, 2) void gemm_u_kernel(
    const unsigned short* __restrict__ Q, const unsigned short* __restrict__ Kb,
    unsigned short* __restrict__ U, float* __restrict__ lpart) {
  __shared__ __align__(16) unsigned short smem[32768];
  gemm_core<2>(Q, 512, Kb, 512, nullptr, U, 8192, 8, 0,
               blockIdx.x * 128, blockIdx.y * 128, lpart, smem);
}

// PV: 1-D grid of 512; c=bid&7 pins (x-tile, k-split) to an XCD so each
// XCD's 1MB VT panel stays L2-hot across all 64 y-steps (XCD = bid%8).
__global__ __launch_bounds__(256, 2) void gemm_pv_kernel(
    const unsigned short* __restrict__ U, const unsigned short* __restrict__ VT,
    float* __restrict__ P0, float* __restrict__ P1) {
  __shared__ __align__(16) unsigned short smem[32768];
  const int b = blockIdx.x;
  const int c = b & 7, xt = c & 3, zt = c >> 2, yt = b >> 3;
  float* P = zt ? P1 : P0;
  gemm_core<0>(U, 8192, VT, 8192, nullptr, P, 512, 64, zt * 4096,
               yt * 128, xt * 128, nullptr, smem);
}

__global__ __launch_bounds__(256, 2) void gemm_o_kernel(
    const unsigned short* __restrict__ att, const unsigned short* __restrict__ woT,
    const float* __restrict__ bo, float* __restrict__ out) {
  __shared__ __align__(16) unsigned short smem[32768];
  gemm_core<0>(att, 512, woT, 512, bo, out, 512, 8, 0,
               blockIdx.x * 128, blockIdx.y * 128, nullptr, smem);
}

// ---------- kernel: v [8192][512] -> vT [512][8192] (bf16) ----------
__global__ void transpose_v_kernel(const unsigned short* __restrict__ in, unsigned short* __restrict__ out) {
  __shared__ unsigned short tile[32][33];
  int tx = threadIdx.x & 31, ty = threadIdx.x >> 5;
  int r0 = blockIdx.y * 32, c0 = blockIdx.x * 32;
#pragma unroll
  for (int i = 0; i < 4; i++) tile[ty + i * 8][tx] = in[(size_t)(r0 + ty + i * 8) * 512 + c0 + tx];
  __syncthreads();
#pragma unroll
  for (int i = 0; i < 4; i++) out[(size_t)(c0 + ty + i * 8) * 8192 + r0 + tx] = tile[tx][ty + i * 8];
}

// ---------- combine row-sum partials -> 1/l ----------
__global__ void combine_l_kernel(const float* __restrict__ lpart, float* __restrict__ linv) {
  int row = blockIdx.x * 256 + threadIdx.x;
  float s = 0.f;
#pragma unroll 8
  for (int j = 0; j < 128; j++) s += lpart[(size_t)j * 8192 + row];
  linv[row] = 1.0f / s;
}

// ---------- add two fp32 partials (optionally * linv[row]) -> bf16 ----------
template <bool NORM>
__global__ void addcvt_kernel(const float* __restrict__ a, const float* __restrict__ b,
                              const float* __restrict__ linv,
                              unsigned short* __restrict__ o, int n4) {
  int i = blockIdx.x * blockDim.x + threadIdx.x;
  int stride = gridDim.x * blockDim.x;
  for (; i < n4; i += stride) {
    float inv = NORM ? linv[i >> 7] : 1.0f;
    float4 va = ((const float4*)a)[i];
    float4 vb = ((const float4*)b)[i];
    ushort4 ov;
    ov.x = f2bf((va.x + vb.x) * inv); ov.y = f2bf((va.y + vb.y) * inv);
    ov.z = f2bf((va.z + vb.z) * inv); ov.w = f2bf((va.w + vb.w) * inv);
    ((ushort4*)o)[i] = ov;
  }
}

// ---------- deep fallback: flash attention ----------
__global__ __launch_bounds__(256, 2) void flash_kernel(
    const unsigned short* __restrict__ Q, const unsigned short* __restrict__ Kb,
    const unsigned short* __restrict__ VT, float* __restrict__ Pout,
    float* __restrict__ ML, int nsLog2) {
  __shared__ __align__(16) unsigned short k_lds[2][32][512];
  __shared__ __align__(16) unsigned short p_lds[4][16][32];
  const int tid = threadIdx.x;
  const int lane = tid & 63, w = tid >> 6;
  const int g = lane >> 4, r = lane & 15;
  const int ns = 1 << nsLog2;
  const int split = blockIdx.x & (ns - 1);
  const int qblk = blockIdx.x >> nsLog2;
  const int qbase = qblk * 64 + w * 16;
  const int kvlen = 8192 >> nsLog2;
  const int kv0 = split * kvlen;
  const int nsteps = kvlen >> 5;
  sh8 qa[16];
#pragma unroll
  for (int dc = 0; dc < 16; dc++)
    qa[dc] = *(const sh8*)&Q[(qbase + r) * 512 + dc * 32 + g * 8];
  f32x4 acc[32] = {};
  float mrow = -1e30f, lrow = 0.f;
  const float K2r = 0.04419417382415922f * 1.4426950408889634f;
#pragma unroll
  for (int ii = 0; ii < 8; ii++) {
    int row = w * 8 + ii;
    gll16(Kb + (size_t)(kv0 + row) * 512 + (size_t)((lane ^ ii) * 8), &k_lds[0][row][0]);
  }
  int cur = 0;
  const int swz = (r & 7) * 8;
  for (int s = 0; s < nsteps; s++) {
    const int kvrow0 = kv0 + s * 32;
    asm volatile("s_waitcnt vmcnt(0)" ::: "memory");
    __syncthreads();
    if (s + 1 < nsteps) {
#pragma unroll
      for (int ii = 0; ii < 8; ii++) {
        int row = w * 8 + ii;
        gll16(Kb + (size_t)(kvrow0 + 32 + row) * 512 + (size_t)((lane ^ ii) * 8),
              &k_lds[cur ^ 1][row][0]);
      }
    }
    f32x4 sA0 = {0.f, 0.f, 0.f, 0.f};
    f32x4 sA1 = {0.f, 0.f, 0.f, 0.f};
#pragma unroll
    for (int dc = 0; dc < 16; dc++) {
      int co = (dc * 32 + g * 8) ^ swz;
      sh8 kf0 = *(const sh8*)&k_lds[cur][r][co];
      sh8 kf1 = *(const sh8*)&k_lds[cur][16 + r][co];
      sA0 = mfma16(kf0, qa[dc], sA0);
      sA1 = mfma16(kf1, qa[dc], sA1);
    }
    float rmax = fmaxf(fmaxf(fmaxf(sA0[0], sA0[1]), fmaxf(sA0[2], sA0[3])),
                       fmaxf(fmaxf(sA1[0], sA1[1]), fmaxf(sA1[2], sA1[3])));
    rmax = fmaxf(rmax, __shfl_xor(rmax, 16));
    rmax = fmaxf(rmax, __shfl_xor(rmax, 32));
    float tmax = rmax * K2r;
    if (__any(tmax > mrow + 4.0f)) {
      float mn = fmaxf(mrow, tmax);
      float corr = __builtin_amdgcn_exp2f(mrow - mn);
      mrow = mn;
      lrow *= corr;
      f32x4 cv;
      cv[0] = __shfl(corr, 4 * g + 0);
      cv[1] = __shfl(corr, 4 * g + 1);
      cv[2] = __shfl(corr, 4 * g + 2);
      cv[3] = __shfl(corr, 4 * g + 3);
#pragma unroll
      for (int dt = 0; dt < 32; dt++) acc[dt] *= cv;
    }
    float p0 = __builtin_amdgcn_exp2f(fmaf(sA0[0], K2r, -mrow));
    float p1 = __builtin_amdgcn_exp2f(fmaf(sA0[1], K2r, -mrow));
    float p2 = __builtin_amdgcn_exp2f(fmaf(sA0[2], K2r, -mrow));
    float p3 = __builtin_amdgcn_exp2f(fmaf(sA0[3], K2r, -mrow));
    float p4 = __builtin_amdgcn_exp2f(fmaf(sA1[0], K2r, -mrow));
    float p5 = __builtin_amdgcn_exp2f(fmaf(sA1[1], K2r, -mrow));
    float p6 = __builtin_amdgcn_exp2f(fmaf(sA1[2], K2r, -mrow));
    float p7 = __builtin_amdgcn_exp2f(fmaf(sA1[3], K2r, -mrow));
    float ps = ((p0 + p1) + (p2 + p3)) + ((p4 + p5) + (p6 + p7));
    ps += __shfl_xor(ps, 16);
    ps += __shfl_xor(ps, 32);
    lrow += ps;
    uint2 w0, w1;
    w0.x = cvtpk(p0, p1); w0.y = cvtpk(p2, p3);
    w1.x = cvtpk(p4, p5); w1.y = cvtpk(p6, p7);
    *(uint2*)&p_lds[w][r][4 * g] = w0;
    *(uint2*)&p_lds[w][r][16 + 4 * g] = w1;
    sh8 pf = *(const sh8*)&p_lds[w][r][8 * g];
#pragma unroll
    for (int dt = 0; dt < 32; dt++) {
      sh8 vf = *(const sh8*)&VT[(dt * 16 + r) * 8192 + kvrow0 + g * 8];
      acc[dt] = mfma16(pf, vf, acc[dt]);
    }
    cur ^= 1;
  }
  float* P = Pout + (size_t)split * 4194304;
#pragma unroll
  for (int dt = 0; dt < 32; dt++)
#pragma unroll
    for (int i = 0; i < 4; i++)
      P[(qbase + 4 * g + i) * 512 + dt * 16 + r] = acc[dt][i];
  if (g == 0) {
    ML[(split * 2 + 0) * 8192 + qbase + r] = mrow;
    ML[(split * 2 + 1) * 8192 + qbase + r] = lrow;
  }
}

template <int NS>
__global__ void combine_kernel(const float* __restrict__ Pp, const float* __restrict__ ML,
                               unsigned short* __restrict__ att) {
  int idx = blockIdx.x * blockDim.x + threadIdx.x;
  int stride = gridDim.x * blockDim.x;
  for (int i4 = idx; i4 < 8192 * 512 / 4; i4 += stride) {
    int row = i4 >> 7;
    float m[NS], l[NS], e[NS];
    float mm = -1e30f;
#pragma unroll
    for (int s2 = 0; s2 < NS; s2++) {
      m[s2] = ML[(s2 * 2 + 0) * 8192 + row];
      l[s2] = ML[(s2 * 2 + 1) * 8192 + row];
      mm = fmaxf(mm, m[s2]);
    }
    float den = 0.f;
#pragma unroll
    for (int s2 = 0; s2 < NS; s2++) {
      e[s2] = __builtin_amdgcn_exp2f(m[s2] - mm);
      den += l[s2] * e[s2];
    }
    float inv = 1.0f / den;
    float ox = 0.f, oy = 0.f, oz = 0.f, ow = 0.f;
#pragma unroll
    for (int s2 = 0; s2 < NS; s2++) {
      float4 a = ((const float4*)(Pp + (size_t)s2 * 4194304))[i4];
      ox += a.x * e[s2]; oy += a.y * e[s2]; oz += a.z * e[s2]; ow += a.w * e[s2];
    }
    ushort4 ov;
    ov.x = f2bf(ox * inv); ov.y = f2bf(oy * inv);
    ov.z = f2bf(oz * inv); ov.w = f2bf(ow * inv);
    ((ushort4*)att)[i4] = ov;
  }
}

// ---------- launch ----------
extern "C" void kernel_launch(void* const* d_in, const int* in_sizes, int n_in,
                              void* d_out, int out_size, void* d_ws, size_t ws_size,
                              hipStream_t stream) {
  const float* x  = (const float*)d_in[0];
  const float* Wq = (const float*)d_in[1];
  const float* bq = (const float*)d_in[2];
  const float* Wk = (const float*)d_in[3];
  const float* bk = (const float*)d_in[4];
  const float* Wv = (const float*)d_in[5];
  const float* bv = (const float*)d_in[6];
  const float* Wo = (const float*)d_in[7];
  const float* bo = (const float*)d_in[8];
  char* ws = (char*)d_ws;

  if (ws_size >= 165707776ull) {
    // ---- Path A2: GEMM attention, softmax fused into U-GEMM epilogue ----
    unsigned short* U   = (unsigned short*)(ws + 0);          // 134.2 MB
    unsigned short* xb  = (unsigned short*)(ws + 0);          // overlay (dead after QKV)
    unsigned short* vb  = (unsigned short*)(ws + 8388608);    // overlay (dead after transp)
    unsigned short* att = (unsigned short*)(ws + 0);          // overlay (after PV)
    unsigned short* qb  = (unsigned short*)(ws + 134217728);
    unsigned short* kb  = (unsigned short*)(ws + 142606336);
    unsigned short* vtb = (unsigned short*)(ws + 150994944);
    unsigned short* wqT = (unsigned short*)(ws + 159383552);
    unsigned short* wkT = (unsigned short*)(ws + 159907840);
    unsigned short* wvT = (unsigned short*)(ws + 160432128);
    unsigned short* woT = (unsigned short*)(ws + 160956416);
    float* lpart = (float*)(ws + 161480704);                  // 4 MB [128][8192]
    float* linv  = (float*)(ws + 165675008);                  // 32 KB
    float* P0 = (float*)qb;        // 16 MB over qb+kb (dead after U-GEMM)
    float* P1 = (float*)d_out;     // overwritten by O-proj

    cvt_x_kernel<<<2048, 256, 0, stream>>>(x, xb, 8192 * 512 / 4);
    cvt_wT_kernel<<<dim3(16, 16, 4), 256, 0, stream>>>(Wq, Wk, Wv, Wo, wqT, wkT, wvT, woT);
    gemm_qkv_kernel<<<dim3(64, 4, 3), 256, 0, stream>>>(
        xb, wqT, wkT, wvT, bq, bk, bv, qb, kb, vb);
    transpose_v_kernel<<<dim3(16, 256), 256, 0, stream>>>(vb, vtb);
    gemm_u_kernel<<<dim3(64, 64), 256, 0, stream>>>(qb, kb, U, lpart);
    combine_l_kernel<<<32, 256, 0, stream>>>(lpart, linv);
    gemm_pv_kernel<<<512, 256, 0, stream>>>(U, vtb, P0, P1);
    addcvt_kernel<true><<<2048, 256, 0, stream>>>(P0, P1, linv, att, 8192 * 512 / 4);
    gemm_o_kernel<<<dim3(64, 4), 256, 0, stream>>>(att, woT, bo, (float*)d_out);
  } else {
    // ---- Path B: flash fallback ----
    unsigned short* xb  = (unsigned short*)(ws + 0);
    unsigned short* qb  = (unsigned short*)(ws + 8388608);
    unsigned short* kb  = (unsigned short*)(ws + 16777216);
    unsigned short* vb  = (unsigned short*)(ws + 25165824);
    unsigned short* vtb = (unsigned short*)(ws + 33554432);
    unsigned short* att = (unsigned short*)(ws + 41943040);
    unsigned short* wqT = (unsigned short*)(ws + 50331648);
    unsigned short* wkT = (unsigned short*)(ws + 50855936);
    unsigned short* wvT = (unsigned short*)(ws + 51380224);
    unsigned short* woT = (unsigned short*)(ws + 51904512);
    float* ml   = (float*)(ws + 52428800);
    float* part = (float*)(ws + 52690944);
    int nsLog2 = (ws_size >= 119900000ull) ? 2 : 1;
    int NS = 1 << nsLog2;

    cvt_x_kernel<<<2048, 256, 0, stream>>>(x, xb, 8192 * 512 / 4);
    cvt_wT_kernel<<<dim3(16, 16, 4), 256, 0, stream>>>(Wq, Wk, Wv, Wo, wqT, wkT, wvT, woT);
    gemm_qkv_kernel<<<dim3(64, 4, 3), 256, 0, stream>>>(
        xb, wqT, wkT, wvT, bq, bk, bv, qb, kb, vb);
    transpose_v_kernel<<<dim3(16, 256), 256, 0, stream>>>(vb, vtb);
    flash_kernel<<<128 * NS, 256, 0, stream>>>(qb, kb, vtb, part, ml, nsLog2);
    if (NS == 4) combine_kernel<4><<<1024, 256, 0, stream>>>(part, ml, att);
    else         combine_kernel<2><<<1024, 256, 0, stream>>>(part, ml, att);
    gemm_o_kernel<<<dim3(64, 4), 256, 0, stream>>>(att, woT, bo, (float*)d_out);
  }
}